// Round 1
// 407.905 us; speedup vs baseline: 1.1409x; 1.1409x over previous
//
#include <hip/hip_runtime.h>
#include <math.h>

#define BN    2456
#define LSEQ  12
#define DM    128
#define NODES 307
#define MROWS 29472   // BN * LSEQ

typedef __bf16 bfx8 __attribute__((ext_vector_type(8)));
typedef float  f32x4 __attribute__((ext_vector_type(4)));

#define MFMA16(a, b, c) __builtin_amdgcn_mfma_f32_16x16x32_bf16(a, b, c, 0, 0, 0)

__device__ __forceinline__ float fsilu(float v)     { return v / (1.0f + __expf(-v)); }
__device__ __forceinline__ float fsoftplus(float x) { return fmaxf(x, 0.f) + __logf(1.0f + __expf(-fabsf(x))); }

// ---------------- K0: convert + pre-swizzle weights into MFMA fragment order ----------------
// Fragment layout: for frag (nt,kc): elem[((nt*4+kc)*64 + lane)*8 + j] = W[nt*16+(lane&15)][kc*32+(lane>>4)*8+j]
__global__ __launch_bounds__(256)
void k_convert(const float* __restrict__ in_w, const float* __restrict__ x_w,
               const float* __restrict__ dt_w, const float* __restrict__ out_w,
               const float* __restrict__ graph,
               __bf16* __restrict__ in_w_sw, __bf16* __restrict__ x_w_sw,
               __bf16* __restrict__ dtw_sw, __bf16* __restrict__ out_w_sw,
               __bf16* __restrict__ graph_sw) {
    int idx = blockIdx.x * 256 + threadIdx.x;
    if (idx < 131072) {            // in_w: 4e x 16nt x 4kc (K=128)
        int o = idx;
        int e = o >> 15, r = o & 32767;
        int frag = r >> 9, lane = (r >> 3) & 63, j = r & 7;
        int nt = frag >> 2, kc = frag & 3, lm = lane & 15, lq = lane >> 4;
        in_w_sw[o] = (__bf16)in_w[e * 32768 + (nt * 16 + lm) * 128 + kc * 32 + lq * 8 + j];
        return;
    }
    idx -= 131072;
    if (idx < 98304) {             // x_w: 4e x 12nt x 4kc (K=128)
        int o = idx;
        int e = o / 24576, r = o - e * 24576;
        int frag = r >> 9, lane = (r >> 3) & 63, j = r & 7;
        int nt = frag >> 2, kc = frag & 3, lm = lane & 15, lq = lane >> 4;
        x_w_sw[o] = (__bf16)x_w[e * 24576 + (nt * 16 + lm) * 128 + kc * 32 + lq * 8 + j];
        return;
    }
    idx -= 98304;
    if (idx < 16384) {             // dt_w: 4e x 8nt (K=32)
        int o = idx;
        int e = o >> 12, r = o & 4095;
        int nt = r >> 9, lane = (r >> 3) & 63, j = r & 7;
        int lm = lane & 15, lq = lane >> 4;
        dtw_sw[o] = (__bf16)dt_w[e * 4096 + (nt * 16 + lm) * 32 + lq * 8 + j];
        return;
    }
    idx -= 16384;
    if (idx < 65536) {             // out_w: 4e x 8nt x 4kc (K=128)
        int o = idx;
        int e = o >> 14, r = o & 16383;
        int frag = r >> 9, lane = (r >> 3) & 63, j = r & 7;
        int f = frag >> 2, kc = frag & 3, lm = lane & 15, lq = lane >> 4;
        out_w_sw[o] = (__bf16)out_w[e * 16384 + (f * 16 + lm) * 128 + kc * 32 + lq * 8 + j];
        return;
    }
    idx -= 65536;
    if (idx < 1572864) {           // graph: 96bl x 8nt x 4kc ; B-operand cols=a, K=d
        int o = idx;
        int bl = o >> 14, r = o & 16383;
        int frag = r >> 9, lane = (r >> 3) & 63, j = r & 7;
        int nt = frag >> 2, kc = frag & 3, lm = lane & 15, lq = lane >> 4;
        int a = nt * 16 + lm, d = kc * 32 + lq * 8 + j;
        graph_sw[o] = (__bf16)graph[(size_t)bl * 16384 + d * 128 + a];
    }
}

// ---------------- block reductions over 128 threads (2 waves) ----------------
template <int N>
__device__ __forceinline__ void red_sum128(float* v, float* sred, int tid) {
#pragma unroll
    for (int off = 32; off; off >>= 1)
#pragma unroll
        for (int i = 0; i < N; ++i) v[i] += __shfl_xor(v[i], off, 64);
    if ((tid & 63) == 0) {
#pragma unroll
        for (int i = 0; i < N; ++i) sred[(tid >> 6) * N + i] = v[i];
    }
    __syncthreads();
#pragma unroll
    for (int i = 0; i < N; ++i) v[i] = sred[i] + sred[N + i];
    __syncthreads();
}

template <int N>
__device__ __forceinline__ void red_max128(float* v, float* sred, int tid) {
#pragma unroll
    for (int off = 32; off; off >>= 1)
#pragma unroll
        for (int i = 0; i < N; ++i) v[i] = fmaxf(v[i], __shfl_xor(v[i], off, 64));
    if ((tid & 63) == 0) {
#pragma unroll
        for (int i = 0; i < N; ++i) sred[(tid >> 6) * N + i] = v[i];
    }
    __syncthreads();
#pragma unroll
    for (int i = 0; i < N; ++i) v[i] = fmaxf(sred[i], sred[N + i]);
    __syncthreads();
}

// ---------------- K1: rmsnorm + in_proj + silu + x_proj + dt_proj + graph-mix ----------------
// grid (96, 20) x 256 (4 waves). block = (b,l) x 16-node tile.
__global__ __launch_bounds__(256)
void k_fused(const float* __restrict__ xcur, const float* __restrict__ norm_w,
             const __bf16* __restrict__ WiSw, const float* __restrict__ in_b,
             const __bf16* __restrict__ WxSw, const __bf16* __restrict__ DWSw,
             const float* __restrict__ dt_b, const __bf16* __restrict__ GSw,
             __bf16* __restrict__ xs_bf, __bf16* __restrict__ sz_bf,
             float* __restrict__ bcf32, __bf16* __restrict__ dpf,
             __bf16* __restrict__ dmix_bf, int e) {
    __shared__ __bf16 sxs[16 * 136];
    __shared__ __bf16 sdelta[16 * 136];
    __shared__ __bf16 sdel32[16 * 40];
    const int bl = blockIdx.x;
    const int n0 = blockIdx.y * 16;
    const int tid = threadIdx.x;
    const int wave = tid >> 6, lane = tid & 63;
    const int lm = lane & 15, lq = lane >> 4;
    const int b = bl / 12, l = bl - b * 12;
    const size_t rowbase = (size_t)bl * NODES + n0;

    // ---- phase 0: rmsnorm from x (f32) -> A fragments in registers ----
    const int nodeA = min(n0 + lm, NODES - 1);
    const float* xrow = xcur + ((size_t)(b * NODES + nodeA) * 12 + l) * 128 + lq * 8;
    float xv[4][8];
#pragma unroll
    for (int kc = 0; kc < 4; ++kc) {
        float4 p0 = *(const float4*)(xrow + kc * 32);
        float4 p1 = *(const float4*)(xrow + kc * 32 + 4);
        xv[kc][0] = p0.x; xv[kc][1] = p0.y; xv[kc][2] = p0.z; xv[kc][3] = p0.w;
        xv[kc][4] = p1.x; xv[kc][5] = p1.y; xv[kc][6] = p1.z; xv[kc][7] = p1.w;
    }
    float ss = 0.f;
#pragma unroll
    for (int kc = 0; kc < 4; ++kc)
#pragma unroll
        for (int j = 0; j < 8; ++j) ss += xv[kc][j] * xv[kc][j];
    ss += __shfl_xor(ss, 16, 64);
    ss += __shfl_xor(ss, 32, 64);
    const float rms = rsqrtf(ss * (1.0f / 128.0f) + 1e-5f);

    bfx8 af[4];
    const float* nwp = norm_w + e * DM + lq * 8;
#pragma unroll
    for (int kc = 0; kc < 4; ++kc) {
        float4 w0 = *(const float4*)(nwp + kc * 32);
        float4 w1 = *(const float4*)(nwp + kc * 32 + 4);
        af[kc][0] = (__bf16)(xv[kc][0] * rms * w0.x);
        af[kc][1] = (__bf16)(xv[kc][1] * rms * w0.y);
        af[kc][2] = (__bf16)(xv[kc][2] * rms * w0.z);
        af[kc][3] = (__bf16)(xv[kc][3] * rms * w0.w);
        af[kc][4] = (__bf16)(xv[kc][4] * rms * w1.x);
        af[kc][5] = (__bf16)(xv[kc][5] * rms * w1.y);
        af[kc][6] = (__bf16)(xv[kc][6] * rms * w1.z);
        af[kc][7] = (__bf16)(xv[kc][7] * rms * w1.w);
    }

    // ---- prefetch phase-2 B fragments (independent of phase 1) ----
    const __bf16* WxP = WxSw + (size_t)e * 24576;
    bfx8 b2[3][4];
#pragma unroll
    for (int ntl = 0; ntl < 3; ++ntl)
#pragma unroll
        for (int kc = 0; kc < 4; ++kc)
            b2[ntl][kc] = *(const bfx8*)(WxP + (((wave * 3 + ntl) * 4 + kc) * 64 + lane) * 8);

    // ---- phase 1: in_proj (coalesced fragment loads) ----
    const __bf16* WiP = WiSw + (size_t)e * 32768;
    f32x4 acc[4];
#pragma unroll
    for (int nt = 0; nt < 4; ++nt) acc[nt] = (f32x4){0.f, 0.f, 0.f, 0.f};
#pragma unroll
    for (int ntl = 0; ntl < 4; ++ntl) {
        const int nt = wave * 4 + ntl;
#pragma unroll
        for (int kc = 0; kc < 4; ++kc) {
            bfx8 bb = *(const bfx8*)(WiP + ((nt * 4 + kc) * 64 + lane) * 8);
            acc[ntl] = MFMA16(af[kc], bb, acc[ntl]);
        }
    }

    // ---- prefetch phase-3 + phase-4 B fragments ----
    const __bf16* DWp = DWSw + (size_t)e * 4096;
    bfx8 b3[2];
#pragma unroll
    for (int ntl = 0; ntl < 2; ++ntl)
        b3[ntl] = *(const bfx8*)(DWp + ((wave * 2 + ntl) * 64 + lane) * 8);
    const __bf16* Gp = GSw + (size_t)bl * 16384;
    bfx8 b4[2][4];
#pragma unroll
    for (int ntl = 0; ntl < 2; ++ntl)
#pragma unroll
        for (int kc = 0; kc < 4; ++kc)
            b4[ntl][kc] = *(const bfx8*)(Gp + (((wave * 2 + ntl) * 4 + kc) * 64 + lane) * 8);

    // ---- phase 1 epilogue ----
#pragma unroll
    for (int ntl = 0; ntl < 4; ++ntl) {
        const int col = wave * 64 + ntl * 16 + lm;
        const float bias = in_b[e * 256 + col];
#pragma unroll
        for (int r = 0; r < 4; ++r) {
            const int node = lq * 4 + r;
            const float v = fsilu(acc[ntl][r] + bias);
            const int ok = (n0 + node) < NODES;
            if (col < 128) {
                sxs[node * 136 + col] = (__bf16)v;
                if (ok) xs_bf[(rowbase + node) * 128 + col] = (__bf16)v;
            } else if (ok) {
                sz_bf[(rowbase + node) * 128 + (col - 128)] = (__bf16)v;
            }
        }
    }
    __syncthreads();

    // ---- phase 2: x_proj, A from LDS, B prefetched ----
    bfx8 ax[4];
#pragma unroll
    for (int kc = 0; kc < 4; ++kc)
        ax[kc] = *(const bfx8*)(sxs + lm * 136 + kc * 32 + lq * 8);

    f32x4 xacc[3];
#pragma unroll
    for (int nt = 0; nt < 3; ++nt) xacc[nt] = (f32x4){0.f, 0.f, 0.f, 0.f};
#pragma unroll
    for (int ntl = 0; ntl < 3; ++ntl)
#pragma unroll
        for (int kc = 0; kc < 4; ++kc)
            xacc[ntl] = MFMA16(ax[kc], b2[ntl][kc], xacc[ntl]);

#pragma unroll
    for (int ntl = 0; ntl < 3; ++ntl) {
        const int col = (wave * 3 + ntl) * 16 + lm;
#pragma unroll
        for (int r = 0; r < 4; ++r) {
            const int node = lq * 4 + r;
            const float v = xacc[ntl][r];
            const int ok = (n0 + node) < NODES;
            if (col < 32) sdel32[node * 40 + col] = (__bf16)v;
            else if (col < 64) { if (ok) bcf32[(rowbase + node) * 32 + (col - 32)] = v; }
            else if (ok) dpf[(rowbase + node) * 128 + (col - 64)] = (__bf16)v;
        }
    }
    __syncthreads();

    // ---- phase 3: dt projection (K=32) ----
    bfx8 ad = *(const bfx8*)(sdel32 + lm * 40 + lq * 8);
    const f32x4 z4 = {0.f, 0.f, 0.f, 0.f};
#pragma unroll
    for (int ntl = 0; ntl < 2; ++ntl) {
        f32x4 dacc = MFMA16(ad, b3[ntl], z4);
        const int col = (wave * 2 + ntl) * 16 + lm;
        const float bias = dt_b[e * 128 + col];
#pragma unroll
        for (int r = 0; r < 4; ++r) {
            const int node = lq * 4 + r;
            sdelta[node * 136 + col] = (__bf16)fsoftplus(dacc[r] + bias);
        }
    }
    __syncthreads();

    // ---- phase 4: graph mix ----
    bfx8 ag[4];
#pragma unroll
    for (int kc = 0; kc < 4; ++kc)
        ag[kc] = *(const bfx8*)(sdelta + lm * 136 + kc * 32 + lq * 8);

#pragma unroll
    for (int ntl = 0; ntl < 2; ++ntl) {
        f32x4 gacc = z4;
#pragma unroll
        for (int kc = 0; kc < 4; ++kc)
            gacc = MFMA16(ag[kc], b4[ntl][kc], gacc);
        const int col = (wave * 2 + ntl) * 16 + lm;
#pragma unroll
        for (int r = 0; r < 4; ++r) {
            const int node = lq * 4 + r;
            if ((n0 + node) < NODES)
                dmix_bf[(rowbase + node) * 128 + col] = (__bf16)gacc[r];
        }
    }
}

// ---------------- K2: freq gating + SSM scan + gate + out_proj + residual ----------------
// grid (2456) x 128 (2 waves). One (b,n) row; xfq never leaves registers.
__global__ __launch_bounds__(128)
void k_scanout(const float* __restrict__ xcur, const float* __restrict__ norm_w,
               const float* __restrict__ fw_r, const float* __restrict__ fw_i,
               const __bf16* __restrict__ dmix_bf, const __bf16* __restrict__ xs_bf,
               const __bf16* __restrict__ sz_bf, const float* __restrict__ bcf32,
               const __bf16* __restrict__ dpf, const float* __restrict__ A_log,
               const __bf16* __restrict__ WoSw, const float* __restrict__ out_b,
               const float* __restrict__ blk_w, const float* __restrict__ blk_b,
               float* __restrict__ xout, int e, int last) {
    __shared__ float s_c[24], s_s[24], s_wr[133], s_wi[133];
    __shared__ float sred[24];
    __shared__ __bf16 s_out[16 * 136];
    __shared__ float sBC[384];
    const int row = blockIdx.x, tid = threadIdx.x;
    const int b = row / NODES, n = row - b * NODES;

    // early-issue the B/C loads for the scan (hidden under freq compute)
    float bcreg[3];
#pragma unroll
    for (int i = 0; i < 3; ++i) {
        const int ii = tid + i * 128;
        const int l = ii >> 5, s = ii & 31;
        bcreg[i] = bcf32[((size_t)(b * 12 + l) * NODES + n) * 32 + s];
    }

    if (tid < 24) {
        float sv, cv;
        __sincosf(6.283185307179586f * (float)tid / 24.0f, &sv, &cv);
        s_c[tid] = cv; s_s[tid] = sv;
    }
    for (int i = tid; i < 133; i += 128) { s_wr[i] = fw_r[e * 133 + i]; s_wi[i] = fw_i[e * 133 + i]; }

    const float* xp = xcur + (size_t)row * 1536 + tid;
    float xvf[12], v[12];
#pragma unroll
    for (int l = 0; l < 12; ++l) { xvf[l] = xp[l * 128]; v[l] = xvf[l] * xvf[l]; }
    __syncthreads();                 // publish tables
    red_sum128<12>(v, sred, tid);

    const float nrmw = norm_w[e * DM + tid];
    float xnr[12];
#pragma unroll
    for (int l = 0; l < 12; ++l)
        xnr[l] = xvf[l] * rsqrtf(v[l] * (1.0f / 128.0f) + 1e-5f) * nrmw;

    // DFT n=24 padded, 13 bins; f (n=12) = fp at even bins (exact dedup)
    float fpr[13], fpi[13];
#pragma unroll
    for (int k = 0; k < 13; ++k) { fpr[k] = 0.f; fpi[k] = 0.f; }
#pragma unroll
    for (int l = 0; l < 12; ++l) {
#pragma unroll
        for (int k = 0; k < 13; ++k) {
            const int t = (k * l) % 24;
            fpr[k] += xnr[l] * s_c[t];
            fpi[k] -= xnr[l] * s_s[t];
        }
    }

    float a7[7];
#pragma unroll
    for (int o2 = 0; o2 < 7; ++o2) {
        float ar = fpr[2 * o2] + 1e-6f, ai = fpi[2 * o2] + 1e-6f;
        a7[o2] = ar * ar + ai * ai;
    }
#pragma unroll
    for (int pss = 0; pss < 6; ++pss)
#pragma unroll
        for (int j = 0; j < 6; ++j) {
            float hi = fmaxf(a7[j], a7[j + 1]);
            float lo = fminf(a7[j], a7[j + 1]);
            a7[j] = hi; a7[j + 1] = lo;
        }

    float p7[7];
#pragma unroll
    for (int o2 = 0; o2 < 7; ++o2) {
        float pr = 0.f, pi = 0.f;
#pragma unroll
        for (int k = 0; k < 13; ++k) {
            const float wr = s_wr[o2 * 19 + k], wi = s_wi[o2 * 19 + k];
            pr += fpr[k] * wr - fpi[k] * wi;
            pi += fpr[k] * wi + fpi[k] * wr;
        }
#pragma unroll
        for (int k = 0; k < 6; ++k) {
            const float wr = s_wr[o2 * 19 + 13 + k], wi = s_wi[o2 * 19 + 13 + k];
            pr += a7[k] * wr;
            pi += a7[k] * wi;
        }
        p7[o2] = pr * pr + pi * pi;
    }

    float m7[7], ex[7], sm[7];
#pragma unroll
    for (int o2 = 0; o2 < 7; ++o2) m7[o2] = p7[o2];
    red_max128<7>(m7, sred, tid);
#pragma unroll
    for (int o2 = 0; o2 < 7; ++o2) { ex[o2] = __expf(p7[o2] - m7[o2]); sm[o2] = ex[o2]; }
    red_sum128<7>(sm, sred, tid);

    float gr[7], gi[7];
#pragma unroll
    for (int o2 = 0; o2 < 7; ++o2) {
        const float wf = ex[o2] / sm[o2];
        gr[o2] = wf * fpr[2 * o2];
        gi[o2] = wf * fpi[2 * o2];
    }

    float xfqv[12];
#pragma unroll
    for (int l = 0; l < 12; ++l) {
        float val = gr[0] + ((l & 1) ? -gr[6] : gr[6]);
#pragma unroll
        for (int o2 = 1; o2 < 6; ++o2) {
            const int t = (2 * o2 * l) % 24;
            val += 2.0f * (gr[o2] * s_c[t] - gi[o2] * s_s[t]);
        }
        xfqv[l] = val * (1.0f / 12.0f);
    }

    // ---- publish B/C + zero pad rows for out_proj A-tile ----
#pragma unroll
    for (int i = 0; i < 3; ++i) sBC[tid + i * 128] = bcreg[i];
#pragma unroll
    for (int r = 12; r < 16; ++r) s_out[r * 136 + tid] = (__bf16)0.f;
    __syncthreads();

    // ---- SSM scan ----
    float As[16];
#pragma unroll
    for (int s = 0; s < 16; ++s) As[s] = -__expf(A_log[e * 16 + s]);
    float h[16];
#pragma unroll
    for (int s = 0; s < 16; ++s) h[s] = 0.f;
#pragma unroll
    for (int l = 0; l < 12; ++l) {
        const size_t base = ((size_t)(b * 12 + l) * NODES + n) * 128 + tid;
        const float dl = (float)dmix_bf[base];
        const float xsv = (float)xs_bf[base];
        const float Dp = (float)dpf[base];
        const float dlx = dl * xsv;
        float y = 0.f;
#pragma unroll
        for (int s = 0; s < 16; ++s) {
            h[s] = __expf(dl * As[s]) * h[s] + sBC[l * 32 + s] * dlx;
            y += h[s] * sBC[l * 32 + 16 + s];
        }
        y += Dp * xsv;
        const float g = y * (float)sz_bf[base] * xfqv[l];
        s_out[l * 136 + tid] = (__bf16)g;
    }
    __syncthreads();

    // ---- out_proj: N=128 split 64/64 by wave, pre-swizzled weights ----
    const int wave = tid >> 6, lane = tid & 63;
    const int lm = lane & 15, lq = lane >> 4;
    const __bf16* Wop = WoSw + (size_t)e * 16384;
    bfx8 a[4];
#pragma unroll
    for (int kc = 0; kc < 4; ++kc)
        a[kc] = *(const bfx8*)(s_out + lm * 136 + kc * 32 + lq * 8);

    f32x4 acc[4];
#pragma unroll
    for (int nt = 0; nt < 4; ++nt) acc[nt] = (f32x4){0.f, 0.f, 0.f, 0.f};
#pragma unroll
    for (int nt = 0; nt < 4; ++nt) {
        const int f = wave * 4 + nt;
#pragma unroll
        for (int kc = 0; kc < 4; ++kc) {
            bfx8 bb = *(const bfx8*)(Wop + ((f * 4 + kc) * 64 + lane) * 8);
            acc[nt] = MFMA16(a[kc], bb, acc[nt]);
        }
    }

    const float bw = blk_w[e], bb2 = blk_b[e];
#pragma unroll
    for (int nt = 0; nt < 4; ++nt) {
        const int col = wave * 64 + nt * 16 + lm;
        const float ob = out_b[e * 128 + col];
#pragma unroll
        for (int r = 0; r < 4; ++r) {
            const int m = lq * 4 + r;
            if (m < 12) {
                const size_t gi = ((size_t)row * 12 + m) * 128 + col;
                float vv = bw * (acc[nt][r] + ob) + bb2 + xcur[gi];
                if (last) vv = fsilu(vv);
                xout[gi] = vv;
            }
        }
    }
}

extern "C" void kernel_launch(void* const* d_in, const int* in_sizes, int n_in,
                              void* d_out, int out_size, void* d_ws, size_t ws_size,
                              hipStream_t stream) {
    (void)in_sizes; (void)n_in; (void)out_size; (void)ws_size;
    const float* x_in   = (const float*)d_in[0];
    const float* graph  = (const float*)d_in[1];
    const float* in_w   = (const float*)d_in[2];
    const float* in_b   = (const float*)d_in[3];
    const float* x_w    = (const float*)d_in[4];
    const float* dt_w   = (const float*)d_in[5];
    const float* dt_b   = (const float*)d_in[6];
    const float* A_log  = (const float*)d_in[7];
    const float* out_w  = (const float*)d_in[8];
    const float* out_b  = (const float*)d_in[9];
    const float* fw_r   = (const float*)d_in[10];
    const float* fw_i   = (const float*)d_in[11];
    const float* norm_w = (const float*)d_in[12];
    const float* blk_w  = (const float*)d_in[13];
    const float* blk_b  = (const float*)d_in[14];
    float* out = (float*)d_out;

    float* ws = (float*)d_ws;
    size_t o = 0;
    __bf16* in_w_sw  = (__bf16*)(ws + o); o += 131072 / 2;
    __bf16* x_w_sw   = (__bf16*)(ws + o); o += 98304 / 2;
    __bf16* dtw_sw   = (__bf16*)(ws + o); o += 16384 / 2;
    __bf16* out_w_sw = (__bf16*)(ws + o); o += 65536 / 2;
    __bf16* graph_sw = (__bf16*)(ws + o); o += 1572864 / 2;
    const size_t NE = (size_t)MROWS * 128;            // 3,772,416 elements
    __bf16* xs_bf    = (__bf16*)(ws + o); o += NE / 2;
    __bf16* sz_bf    = (__bf16*)(ws + o); o += NE / 2;
    __bf16* dpf      = (__bf16*)(ws + o); o += NE / 2;
    __bf16* dmix_bf  = (__bf16*)(ws + o); o += NE / 2;
    float*  bcf32    = ws + o;            o += (size_t)MROWS * 32;

    // 131072+98304+16384+65536+1572864 = 1,884,160 = 7360 * 256
    hipLaunchKernelGGL(k_convert, dim3(7360), dim3(256), 0, stream,
                       in_w, x_w, dt_w, out_w, graph,
                       in_w_sw, x_w_sw, dtw_sw, out_w_sw, graph_sw);

    for (int e = 0; e < 4; ++e) {
        const float* xcur = (e == 0) ? x_in : (const float*)out;
        const int last = (e == 3) ? 1 : 0;
        hipLaunchKernelGGL(k_fused, dim3(96, 20), dim3(256), 0, stream,
                           xcur, norm_w, in_w_sw, in_b, x_w_sw, dtw_sw, dt_b, graph_sw,
                           xs_bf, sz_bf, bcf32, dpf, dmix_bf, e);
        hipLaunchKernelGGL(k_scanout, dim3(BN), dim3(128), 0, stream,
                           xcur, norm_w, fw_r, fw_i, dmix_bf, xs_bf, sz_bf, bcf32,
                           dpf, A_log, out_w_sw, out_b, blk_w, blk_b, out, e, last);
    }
}

// Round 2
// 399.155 us; speedup vs baseline: 1.1660x; 1.0219x over previous
//
#include <hip/hip_runtime.h>
#include <math.h>

#define BN    2456
#define LSEQ  12
#define DM    128
#define NODES 307
#define MROWS 29472   // BN * LSEQ

typedef __bf16 bfx8 __attribute__((ext_vector_type(8)));
typedef __bf16 bfx4 __attribute__((ext_vector_type(4)));
typedef float  f32x4 __attribute__((ext_vector_type(4)));

#define MFMA16(a, b, c) __builtin_amdgcn_mfma_f32_16x16x32_bf16(a, b, c, 0, 0, 0)

__device__ __forceinline__ float fsilu(float v)     { return v / (1.0f + __expf(-v)); }
__device__ __forceinline__ float fsoftplus(float x) { return fmaxf(x, 0.f) + __logf(1.0f + __expf(-fabsf(x))); }

// ---------------- K0: convert + pre-swizzle weights into MFMA fragment order ----------------
// Fragment layout: for frag (nt,kc): elem[((nt*4+kc)*64 + lane)*8 + j] = W[nt*16+(lane&15)][kc*32+(lane>>4)*8+j]
__global__ __launch_bounds__(256)
void k_convert(const float* __restrict__ in_w, const float* __restrict__ x_w,
               const float* __restrict__ dt_w, const float* __restrict__ out_w,
               const float* __restrict__ graph,
               __bf16* __restrict__ in_w_sw, __bf16* __restrict__ x_w_sw,
               __bf16* __restrict__ dtw_sw, __bf16* __restrict__ out_w_sw,
               __bf16* __restrict__ graph_sw) {
    int idx = blockIdx.x * 256 + threadIdx.x;
    if (idx < 131072) {            // in_w: 4e x 16nt x 4kc (K=128)
        int o = idx;
        int e = o >> 15, r = o & 32767;
        int frag = r >> 9, lane = (r >> 3) & 63, j = r & 7;
        int nt = frag >> 2, kc = frag & 3, lm = lane & 15, lq = lane >> 4;
        in_w_sw[o] = (__bf16)in_w[e * 32768 + (nt * 16 + lm) * 128 + kc * 32 + lq * 8 + j];
        return;
    }
    idx -= 131072;
    if (idx < 98304) {             // x_w: 4e x 12nt x 4kc (K=128)
        int o = idx;
        int e = o / 24576, r = o - e * 24576;
        int frag = r >> 9, lane = (r >> 3) & 63, j = r & 7;
        int nt = frag >> 2, kc = frag & 3, lm = lane & 15, lq = lane >> 4;
        x_w_sw[o] = (__bf16)x_w[e * 24576 + (nt * 16 + lm) * 128 + kc * 32 + lq * 8 + j];
        return;
    }
    idx -= 98304;
    if (idx < 16384) {             // dt_w: 4e x 8nt (K=32)
        int o = idx;
        int e = o >> 12, r = o & 4095;
        int nt = r >> 9, lane = (r >> 3) & 63, j = r & 7;
        int lm = lane & 15, lq = lane >> 4;
        dtw_sw[o] = (__bf16)dt_w[e * 4096 + (nt * 16 + lm) * 32 + lq * 8 + j];
        return;
    }
    idx -= 16384;
    if (idx < 65536) {             // out_w: 4e x 8nt x 4kc (K=128)
        int o = idx;
        int e = o >> 14, r = o & 16383;
        int frag = r >> 9, lane = (r >> 3) & 63, j = r & 7;
        int f = frag >> 2, kc = frag & 3, lm = lane & 15, lq = lane >> 4;
        out_w_sw[o] = (__bf16)out_w[e * 16384 + (f * 16 + lm) * 128 + kc * 32 + lq * 8 + j];
        return;
    }
    idx -= 65536;
    if (idx < 1572864) {           // graph: coalesced read, fragment-order write
        int bl = idx >> 14, r = idx & 16383;
        int dd = r >> 7, a = r & 127;           // src: graph[bl][dd][a], B rows=K=dd, cols=a
        int nt = a >> 4, lm = a & 15, kc = dd >> 5, lq = (dd >> 3) & 3, j = dd & 7;
        graph_sw[(size_t)bl * 16384 + ((size_t)((nt * 4 + kc) * 64 + lq * 16 + lm)) * 8 + j] =
            (__bf16)graph[(size_t)bl * 16384 + dd * 128 + a];
    }
}

// ---------------- reductions over the 128 d-channels (256 threads, d=tid>>1, t=tid&1) ----------------
template <int N>
__device__ __forceinline__ void red_sum256(float* v, float (&sred)[8][8], int lane, int wave, int t) {
#pragma unroll
    for (int off = 2; off <= 32; off <<= 1)
#pragma unroll
        for (int i = 0; i < N; ++i) v[i] += __shfl_xor(v[i], off, 64);
    if (lane < 2) {
#pragma unroll
        for (int i = 0; i < N; ++i) sred[wave * 2 + lane][i] = v[i];
    }
    __syncthreads();
#pragma unroll
    for (int i = 0; i < N; ++i)
        v[i] = sred[t][i] + sred[2 + t][i] + sred[4 + t][i] + sred[6 + t][i];
    __syncthreads();
}

template <int N>
__device__ __forceinline__ void red_max256(float* v, float (&sred)[8][8], int lane, int wave, int t) {
#pragma unroll
    for (int off = 2; off <= 32; off <<= 1)
#pragma unroll
        for (int i = 0; i < N; ++i) v[i] = fmaxf(v[i], __shfl_xor(v[i], off, 64));
    if (lane < 2) {
#pragma unroll
        for (int i = 0; i < N; ++i) sred[wave * 2 + lane][i] = v[i];
    }
    __syncthreads();
#pragma unroll
    for (int i = 0; i < N; ++i)
        v[i] = fmaxf(fmaxf(sred[t][i], sred[2 + t][i]), fmaxf(sred[4 + t][i], sred[6 + t][i]));
    __syncthreads();
}

// ---------------- K1: rmsnorm + in_proj + silu + x_proj + dt_proj + graph-mix ----------------
// grid (96, 20) x 256 (4 waves). block = (b,l) x 16-node tile.
// scanp packs (dl_mix, xs, dp, sz) as 4 x bf16 per (row,node,d).
__global__ __launch_bounds__(256)
void k_fused(const float* __restrict__ xcur, const float* __restrict__ norm_w,
             const __bf16* __restrict__ WiSw, const float* __restrict__ in_b,
             const __bf16* __restrict__ WxSw, const __bf16* __restrict__ DWSw,
             const float* __restrict__ dt_b, const __bf16* __restrict__ GSw,
             __bf16* __restrict__ scanp, float* __restrict__ bcf32, int e) {
    __shared__ __bf16 sxs[16 * 136];
    __shared__ __bf16 sdelta[16 * 136];
    __shared__ __bf16 sdel32[16 * 40];
    __shared__ float sxf[16][132];
    const int bl = blockIdx.x;
    const int n0 = blockIdx.y * 16;
    const int tid = threadIdx.x;
    const int wave = tid >> 6, lane = tid & 63;
    const int lm = lane & 15, lq = lane >> 4;
    const int b = bl / 12, l = bl - b * 12;
    const size_t rowbase = (size_t)bl * NODES + n0;

    // ---- phase 0a: stage the 16x128 x-tile through LDS (contiguous 512B wave reads) ----
    for (int i = tid; i < 1024; i += 256) {
        const int node = i >> 6, dp2 = i & 63;
        const int gn = min(n0 + node, NODES - 1);
        *(float2*)(&sxf[node][dp2 * 2]) =
            *(const float2*)(xcur + ((size_t)(b * NODES + gn) * 12 + l) * 128 + dp2 * 2);
    }
    __syncthreads();

    // ---- phase 0b: rmsnorm -> A fragments in registers ----
    float xv[4][8];
#pragma unroll
    for (int kc = 0; kc < 4; ++kc)
#pragma unroll
        for (int j = 0; j < 8; ++j) xv[kc][j] = sxf[lm][kc * 32 + lq * 8 + j];

    float ss = 0.f;
#pragma unroll
    for (int kc = 0; kc < 4; ++kc)
#pragma unroll
        for (int j = 0; j < 8; ++j) ss += xv[kc][j] * xv[kc][j];
    ss += __shfl_xor(ss, 16, 64);
    ss += __shfl_xor(ss, 32, 64);
    const float rms = rsqrtf(ss * (1.0f / 128.0f) + 1e-5f);

    bfx8 af[4];
    const float* nwp = norm_w + e * DM + lq * 8;
#pragma unroll
    for (int kc = 0; kc < 4; ++kc) {
        float4 w0 = *(const float4*)(nwp + kc * 32);
        float4 w1 = *(const float4*)(nwp + kc * 32 + 4);
        af[kc][0] = (__bf16)(xv[kc][0] * rms * w0.x);
        af[kc][1] = (__bf16)(xv[kc][1] * rms * w0.y);
        af[kc][2] = (__bf16)(xv[kc][2] * rms * w0.z);
        af[kc][3] = (__bf16)(xv[kc][3] * rms * w0.w);
        af[kc][4] = (__bf16)(xv[kc][4] * rms * w1.x);
        af[kc][5] = (__bf16)(xv[kc][5] * rms * w1.y);
        af[kc][6] = (__bf16)(xv[kc][6] * rms * w1.z);
        af[kc][7] = (__bf16)(xv[kc][7] * rms * w1.w);
    }

    // ---- prefetch phase-2 B fragments (independent of phase 1) ----
    const __bf16* WxP = WxSw + (size_t)e * 24576;
    bfx8 b2[3][4];
#pragma unroll
    for (int ntl = 0; ntl < 3; ++ntl)
#pragma unroll
        for (int kc = 0; kc < 4; ++kc)
            b2[ntl][kc] = *(const bfx8*)(WxP + (((wave * 3 + ntl) * 4 + kc) * 64 + lane) * 8);

    // ---- phase 1: in_proj ----
    const __bf16* WiP = WiSw + (size_t)e * 32768;
    f32x4 acc[4];
#pragma unroll
    for (int nt = 0; nt < 4; ++nt) acc[nt] = (f32x4){0.f, 0.f, 0.f, 0.f};
#pragma unroll
    for (int ntl = 0; ntl < 4; ++ntl) {
        const int nt = wave * 4 + ntl;
#pragma unroll
        for (int kc = 0; kc < 4; ++kc) {
            bfx8 bb = *(const bfx8*)(WiP + ((nt * 4 + kc) * 64 + lane) * 8);
            acc[ntl] = MFMA16(af[kc], bb, acc[ntl]);
        }
    }

    // ---- prefetch phase-3 + phase-4 B fragments ----
    const __bf16* DWp = DWSw + (size_t)e * 4096;
    bfx8 b3[2];
#pragma unroll
    for (int ntl = 0; ntl < 2; ++ntl)
        b3[ntl] = *(const bfx8*)(DWp + ((wave * 2 + ntl) * 64 + lane) * 8);
    const __bf16* Gp = GSw + (size_t)bl * 16384;
    bfx8 b4[2][4];
#pragma unroll
    for (int ntl = 0; ntl < 2; ++ntl)
#pragma unroll
        for (int kc = 0; kc < 4; ++kc)
            b4[ntl][kc] = *(const bfx8*)(Gp + (((wave * 2 + ntl) * 4 + kc) * 64 + lane) * 8);

    // ---- phase 1 epilogue ----
#pragma unroll
    for (int ntl = 0; ntl < 4; ++ntl) {
        const int col = wave * 64 + ntl * 16 + lm;
        const float bias = in_b[e * 256 + col];
#pragma unroll
        for (int r = 0; r < 4; ++r) {
            const int node = lq * 4 + r;
            const float v = fsilu(acc[ntl][r] + bias);
            const int ok = (n0 + node) < NODES;
            if (col < 128) {
                sxs[node * 136 + col] = (__bf16)v;
                if (ok) scanp[(rowbase + node) * 512 + col * 4 + 1] = (__bf16)v;
            } else if (ok) {
                scanp[(rowbase + node) * 512 + (col - 128) * 4 + 3] = (__bf16)v;
            }
        }
    }
    __syncthreads();

    // ---- phase 2: x_proj, A from LDS, B prefetched ----
    bfx8 ax[4];
#pragma unroll
    for (int kc = 0; kc < 4; ++kc)
        ax[kc] = *(const bfx8*)(sxs + lm * 136 + kc * 32 + lq * 8);

    f32x4 xacc[3];
#pragma unroll
    for (int nt = 0; nt < 3; ++nt) xacc[nt] = (f32x4){0.f, 0.f, 0.f, 0.f};
#pragma unroll
    for (int ntl = 0; ntl < 3; ++ntl)
#pragma unroll
        for (int kc = 0; kc < 4; ++kc)
            xacc[ntl] = MFMA16(ax[kc], b2[ntl][kc], xacc[ntl]);

#pragma unroll
    for (int ntl = 0; ntl < 3; ++ntl) {
        const int col = (wave * 3 + ntl) * 16 + lm;
#pragma unroll
        for (int r = 0; r < 4; ++r) {
            const int node = lq * 4 + r;
            const float v = xacc[ntl][r];
            const int ok = (n0 + node) < NODES;
            if (col < 32) sdel32[node * 40 + col] = (__bf16)v;
            else if (col < 64) { if (ok) bcf32[(rowbase + node) * 32 + (col - 32)] = v; }
            else if (ok) scanp[(rowbase + node) * 512 + (col - 64) * 4 + 2] = (__bf16)v;
        }
    }
    __syncthreads();

    // ---- phase 3: dt projection (K=32) ----
    bfx8 ad = *(const bfx8*)(sdel32 + lm * 40 + lq * 8);
    const f32x4 z4 = {0.f, 0.f, 0.f, 0.f};
#pragma unroll
    for (int ntl = 0; ntl < 2; ++ntl) {
        f32x4 dacc = MFMA16(ad, b3[ntl], z4);
        const int col = (wave * 2 + ntl) * 16 + lm;
        const float bias = dt_b[e * 128 + col];
#pragma unroll
        for (int r = 0; r < 4; ++r) {
            const int node = lq * 4 + r;
            sdelta[node * 136 + col] = (__bf16)fsoftplus(dacc[r] + bias);
        }
    }
    __syncthreads();

    // ---- phase 4: graph mix ----
    bfx8 ag[4];
#pragma unroll
    for (int kc = 0; kc < 4; ++kc)
        ag[kc] = *(const bfx8*)(sdelta + lm * 136 + kc * 32 + lq * 8);

#pragma unroll
    for (int ntl = 0; ntl < 2; ++ntl) {
        f32x4 gacc = z4;
#pragma unroll
        for (int kc = 0; kc < 4; ++kc)
            gacc = MFMA16(ag[kc], b4[ntl][kc], gacc);
        const int col = (wave * 2 + ntl) * 16 + lm;
#pragma unroll
        for (int r = 0; r < 4; ++r) {
            const int node = lq * 4 + r;
            if ((n0 + node) < NODES)
                scanp[(rowbase + node) * 512 + col * 4 + 0] = (__bf16)gacc[r];
        }
    }
}

// ---------------- K2: freq gating + SSM scan + gate + out_proj + residual ----------------
// grid (2456) x 256 (4 waves). One (b,n) row; channel d = tid>>1, half t = tid&1.
__global__ __launch_bounds__(256, 3)
void k_scanout(const float* __restrict__ xcur, const float* __restrict__ norm_w,
               const float* __restrict__ fw_r, const float* __restrict__ fw_i,
               const __bf16* __restrict__ scanp, const float* __restrict__ bcf32,
               const float* __restrict__ A_log, const __bf16* __restrict__ WoSw,
               const float* __restrict__ out_b, const float* __restrict__ blk_w,
               const float* __restrict__ blk_b, float* __restrict__ xout, int e, int last) {
    __shared__ float s_c[24], s_s[24], s_wr[133], s_wi[133];
    __shared__ float sred[8][8];
    __shared__ __bf16 s_out[16 * 136];
    __shared__ float sBC[384];
    const int row = blockIdx.x, tid = threadIdx.x;
    const int b = row / NODES, n = row - b * NODES;
    const int d = tid >> 1, t = tid & 1, wave = tid >> 6, lane = tid & 63;

    // ---- hoisted scan-input loads: latency hidden under the whole freq section ----
    bfx4 sc12[12];
    const size_t sb = ((size_t)(b * 12) * NODES + n) * 512 + (size_t)d * 4;
#pragma unroll
    for (int l = 0; l < 12; ++l)
        sc12[l] = *(const bfx4*)(scanp + sb + (size_t)l * (NODES * 512));

    const float bc0 = bcf32[((size_t)(b * 12 + (tid >> 5)) * NODES + n) * 32 + (tid & 31)];
    const float bc1 = (tid < 128)
        ? bcf32[((size_t)(b * 12 + (tid >> 5) + 8) * NODES + n) * 32 + (tid & 31)] : 0.f;

    if (tid < 24) {
        float sv, cv;
        __sincosf(6.283185307179586f * (float)tid / 24.0f, &sv, &cv);
        s_c[tid] = cv; s_s[tid] = sv;
    }
    if (tid < 133) { s_wr[tid] = fw_r[e * 133 + tid]; s_wi[tid] = fw_i[e * 133 + tid]; }

    // ---- A structure check (A = -[1..16] -> pow-chain scan) ----
    float As_own[8];
    int chainOK = 1;
#pragma unroll
    for (int s = 0; s < 16; ++s) {
        const float av = __expf(A_log[e * 16 + s]);
        chainOK &= (fabsf(av - (float)(s + 1)) < 1e-3f) ? 1 : 0;
        if ((s >> 3) == t) As_own[s & 7] = -av;
    }

    // ---- rmsnorm over own 6 l's ----
    float xvf[6], v6[6];
#pragma unroll
    for (int ll = 0; ll < 6; ++ll) {
        xvf[ll] = xcur[(size_t)row * 1536 + (t * 6 + ll) * 128 + d];
        v6[ll] = xvf[ll] * xvf[ll];
    }
    red_sum256<6>(v6, sred, lane, wave, t);   // internal barriers also publish the tables

    const float nrmw = norm_w[e * DM + d];
    float xnr[6];
#pragma unroll
    for (int ll = 0; ll < 6; ++ll)
        xnr[ll] = xvf[ll] * rsqrtf(v6[ll] * (1.0f / 128.0f) + 1e-5f) * nrmw;

    // ---- 13-bin DFT (n=24, zero-padded) via twiddle recurrence; halves combined by shfl ----
    float fpr[13], fpi[13];
#pragma unroll
    for (int k = 0; k < 13; ++k) { fpr[k] = 0.f; fpi[k] = 0.f; }
#pragma unroll
    for (int ll = 0; ll < 6; ++ll) {
        const int l = t * 6 + ll;
        const float c1 = s_c[l], s1 = -s_s[l];
        const float x = xnr[ll];
        float wr = 1.f, wi = 0.f;
#pragma unroll
        for (int k = 0; k < 13; ++k) {
            fpr[k] += x * wr; fpi[k] += x * wi;
            const float nr = wr * c1 - wi * s1;
            wi = wr * s1 + wi * c1; wr = nr;
        }
    }
#pragma unroll
    for (int k = 0; k < 13; ++k) {
        fpr[k] += __shfl_xor(fpr[k], 1, 64);
        fpi[k] += __shfl_xor(fpi[k], 1, 64);
    }

    float a7[7];
#pragma unroll
    for (int o2 = 0; o2 < 7; ++o2) {
        const float ar = fpr[2 * o2] + 1e-6f, ai = fpi[2 * o2] + 1e-6f;
        a7[o2] = ar * ar + ai * ai;
    }
#pragma unroll
    for (int pss = 0; pss < 6; ++pss)
#pragma unroll
        for (int j = 0; j < 6; ++j) {
            const float hi = fmaxf(a7[j], a7[j + 1]);
            const float lo = fminf(a7[j], a7[j + 1]);
            a7[j] = hi; a7[j + 1] = lo;
        }

    // ---- freq_proj split by o2 parity: thread handles o2 = 2i+t ----
    float p4[4];
#pragma unroll
    for (int i = 0; i < 4; ++i) {
        const int o2c = min(2 * i + t, 6);
        float pr = 0.f, pi = 0.f;
#pragma unroll
        for (int k = 0; k < 13; ++k) {
            const float wr = s_wr[o2c * 19 + k], wi = s_wi[o2c * 19 + k];
            pr += fpr[k] * wr - fpi[k] * wi;
            pi += fpr[k] * wi + fpi[k] * wr;
        }
#pragma unroll
        for (int k = 0; k < 6; ++k) {
            const float wr = s_wr[o2c * 19 + 13 + k], wi = s_wi[o2c * 19 + 13 + k];
            pr += a7[k] * wr;
            pi += a7[k] * wi;
        }
        p4[i] = pr * pr + pi * pi;
    }

    float m4[4], ex4[4], sm4[4];
#pragma unroll
    for (int i = 0; i < 4; ++i) m4[i] = p4[i];
    red_max256<4>(m4, sred, lane, wave, t);
#pragma unroll
    for (int i = 0; i < 4; ++i) { ex4[i] = __expf(p4[i] - m4[i]); sm4[i] = ex4[i]; }
    red_sum256<4>(sm4, sred, lane, wave, t);

    float grm[4], gim[4];
#pragma unroll
    for (int i = 0; i < 4; ++i) {
        const float frA = fpr[4 * i], frB = (4 * i + 2 <= 12) ? fpr[4 * i + 2] : fpr[12];
        const float fiA = fpi[4 * i], fiB = (4 * i + 2 <= 12) ? fpi[4 * i + 2] : fpi[12];
        const float fr = t ? frB : frA;
        const float fi = t ? fiB : fiA;
        const float wf = ex4[i] / sm4[i];
        grm[i] = wf * fr; gim[i] = wf * fi;
    }
    // exchange with partner -> full gr/gi for o2=0..6
    float grx[7], gix[7];
#pragma unroll
    for (int i = 0; i < 4; ++i) {
        const float a = grm[i], ash = __shfl_xor(grm[i], 1, 64);
        const float g = gim[i], gsh = __shfl_xor(gim[i], 1, 64);
        if (2 * i <= 6)     { grx[2 * i] = t ? ash : a; gix[2 * i] = t ? gsh : g; }
        if (2 * i + 1 <= 6) { grx[2 * i + 1] = t ? a : ash; gix[2 * i + 1] = t ? g : gsh; }
    }

    // ---- irfft reconstruction (duplicated across t) ----
    float xfqv[12];
#pragma unroll
    for (int l = 0; l < 12; ++l) {
        const float c1 = s_c[(2 * l) % 24], s1 = s_s[(2 * l) % 24];
        float wr = c1, wi = s1;
        float val = grx[0] + ((l & 1) ? -grx[6] : grx[6]);
#pragma unroll
        for (int o2 = 1; o2 < 6; ++o2) {
            val += 2.0f * (grx[o2] * wr - gix[o2] * wi);
            const float nr = wr * c1 - wi * s1;
            wi = wr * s1 + wi * c1; wr = nr;
        }
        xfqv[l] = val * (1.0f / 12.0f);
    }

    // ---- publish B/C + zero pad rows ----
    sBC[tid] = bc0;
    if (tid < 128) {
        sBC[tid + 256] = bc1;
#pragma unroll
        for (int r = 12; r < 16; ++r) s_out[r * 136 + tid] = (__bf16)0.f;
    }
    __syncthreads();

    // ---- SSM scan: 8 states per thread, y combined via shfl ----
    float h[8];
#pragma unroll
    for (int j = 0; j < 8; ++j) h[j] = 0.f;

    if (chainOK) {
#pragma unroll
        for (int l = 0; l < 12; ++l) {
            const float dl = (float)sc12[l][0], xv = (float)sc12[l][1];
            const float dlx = dl * xv;
            float Bj[8], Cj[8];
            *(float4*)&Bj[0] = *(const float4*)(sBC + l * 32 + t * 8);
            *(float4*)&Bj[4] = *(const float4*)(sBC + l * 32 + t * 8 + 4);
            *(float4*)&Cj[0] = *(const float4*)(sBC + l * 32 + 16 + t * 8);
            *(float4*)&Cj[4] = *(const float4*)(sBC + l * 32 + 16 + t * 8 + 4);
            const float q = __expf(-dl);
            const float q2 = q * q, q4 = q2 * q2, q8 = q4 * q4;
            float p = t ? q8 * q : q;       // q^(8t+1)
            float y = 0.f;
#pragma unroll
            for (int j = 0; j < 8; ++j) {
                h[j] = p * h[j] + Bj[j] * dlx;
                y += h[j] * Cj[j];
                p *= q;
            }
            y += __shfl_xor(y, 1, 64);
            y += (float)sc12[l][2] * xv;
            const float g = y * (float)sc12[l][3] * xfqv[l];
            if (t == 0) s_out[l * 136 + d] = (__bf16)g;
        }
    } else {
#pragma unroll
        for (int l = 0; l < 12; ++l) {
            const float dl = (float)sc12[l][0], xv = (float)sc12[l][1];
            const float dlx = dl * xv;
            float Bj[8], Cj[8];
            *(float4*)&Bj[0] = *(const float4*)(sBC + l * 32 + t * 8);
            *(float4*)&Bj[4] = *(const float4*)(sBC + l * 32 + t * 8 + 4);
            *(float4*)&Cj[0] = *(const float4*)(sBC + l * 32 + 16 + t * 8);
            *(float4*)&Cj[4] = *(const float4*)(sBC + l * 32 + 16 + t * 8 + 4);
            float y = 0.f;
#pragma unroll
            for (int j = 0; j < 8; ++j) {
                const float a = __expf(dl * As_own[j]);
                h[j] = a * h[j] + Bj[j] * dlx;
                y += h[j] * Cj[j];
            }
            y += __shfl_xor(y, 1, 64);
            y += (float)sc12[l][2] * xv;
            const float g = y * (float)sc12[l][3] * xfqv[l];
            if (t == 0) s_out[l * 136 + d] = (__bf16)g;
        }
    }
    __syncthreads();

    // ---- out_proj: N=128 split 32/wave over 4 waves, pre-swizzled weights ----
    const int lm = lane & 15, lq = lane >> 4;
    const __bf16* Wop = WoSw + (size_t)e * 16384;
    bfx8 a[4];
#pragma unroll
    for (int kc = 0; kc < 4; ++kc)
        a[kc] = *(const bfx8*)(s_out + lm * 136 + kc * 32 + lq * 8);

    f32x4 acc[2];
#pragma unroll
    for (int nt = 0; nt < 2; ++nt) acc[nt] = (f32x4){0.f, 0.f, 0.f, 0.f};
#pragma unroll
    for (int nt = 0; nt < 2; ++nt) {
        const int f = wave * 2 + nt;
#pragma unroll
        for (int kc = 0; kc < 4; ++kc) {
            bfx8 bb = *(const bfx8*)(Wop + ((f * 4 + kc) * 64 + lane) * 8);
            acc[nt] = MFMA16(a[kc], bb, acc[nt]);
        }
    }

    const float bw = blk_w[e], bb2 = blk_b[e];
#pragma unroll
    for (int nt = 0; nt < 2; ++nt) {
        const int col = wave * 32 + nt * 16 + lm;
        const float ob = out_b[e * 128 + col];
#pragma unroll
        for (int r = 0; r < 4; ++r) {
            const int m = lq * 4 + r;
            if (m < 12) {
                const size_t gi = (size_t)row * 1536 + m * 128 + col;
                float vv = bw * (acc[nt][r] + ob) + bb2 + xcur[gi];
                if (last) vv = fsilu(vv);
                xout[gi] = vv;
            }
        }
    }
}

extern "C" void kernel_launch(void* const* d_in, const int* in_sizes, int n_in,
                              void* d_out, int out_size, void* d_ws, size_t ws_size,
                              hipStream_t stream) {
    (void)in_sizes; (void)n_in; (void)out_size; (void)ws_size;
    const float* x_in   = (const float*)d_in[0];
    const float* graph  = (const float*)d_in[1];
    const float* in_w   = (const float*)d_in[2];
    const float* in_b   = (const float*)d_in[3];
    const float* x_w    = (const float*)d_in[4];
    const float* dt_w   = (const float*)d_in[5];
    const float* dt_b   = (const float*)d_in[6];
    const float* A_log  = (const float*)d_in[7];
    const float* out_w  = (const float*)d_in[8];
    const float* out_b  = (const float*)d_in[9];
    const float* fw_r   = (const float*)d_in[10];
    const float* fw_i   = (const float*)d_in[11];
    const float* norm_w = (const float*)d_in[12];
    const float* blk_w  = (const float*)d_in[13];
    const float* blk_b  = (const float*)d_in[14];
    float* out = (float*)d_out;

    float* ws = (float*)d_ws;
    size_t o = 0;
    __bf16* in_w_sw  = (__bf16*)(ws + o); o += 131072 / 2;
    __bf16* x_w_sw   = (__bf16*)(ws + o); o += 98304 / 2;
    __bf16* dtw_sw   = (__bf16*)(ws + o); o += 16384 / 2;
    __bf16* out_w_sw = (__bf16*)(ws + o); o += 65536 / 2;
    __bf16* graph_sw = (__bf16*)(ws + o); o += 1572864 / 2;
    __bf16* scanp    = (__bf16*)(ws + o); o += (size_t)MROWS * 512 / 2;  // (dl,xs,dp,sz) x bf16
    float*  bcf32    = ws + o;            o += (size_t)MROWS * 32;

    // 131072+98304+16384+65536+1572864 = 1,884,160 = 7360 * 256
    hipLaunchKernelGGL(k_convert, dim3(7360), dim3(256), 0, stream,
                       in_w, x_w, dt_w, out_w, graph,
                       in_w_sw, x_w_sw, dtw_sw, out_w_sw, graph_sw);

    for (int e = 0; e < 4; ++e) {
        const float* xcur = (e == 0) ? x_in : (const float*)out;
        const int last = (e == 3) ? 1 : 0;
        hipLaunchKernelGGL(k_fused, dim3(96, 20), dim3(256), 0, stream,
                           xcur, norm_w, in_w_sw, in_b, x_w_sw, dtw_sw, dt_b, graph_sw,
                           scanp, bcf32, e);
        hipLaunchKernelGGL(k_scanout, dim3(BN), dim3(256), 0, stream,
                           xcur, norm_w, fw_r, fw_i, scanp, bcf32, A_log,
                           out_w_sw, out_b, blk_w, blk_b, out, e, last);
    }
}

// Round 3
// 382.282 us; speedup vs baseline: 1.2174x; 1.0441x over previous
//
#include <hip/hip_runtime.h>
#include <math.h>

#define BN    2456
#define LSEQ  12
#define DM    128
#define NODES 307
#define MROWS 29472   // BN * LSEQ

typedef __bf16 bfx8 __attribute__((ext_vector_type(8)));
typedef __bf16 bfx4 __attribute__((ext_vector_type(4)));
typedef float  f32x4 __attribute__((ext_vector_type(4)));

#define MFMA16(a, b, c) __builtin_amdgcn_mfma_f32_16x16x32_bf16(a, b, c, 0, 0, 0)

__device__ __forceinline__ float fsilu(float v)     { return v / (1.0f + __expf(-v)); }
__device__ __forceinline__ float fsoftplus(float x) { return fmaxf(x, 0.f) + __logf(1.0f + __expf(-fabsf(x))); }

// ---------------- K0: convert + pre-swizzle weights into MFMA fragment order ----------------
// Also folds freq_proj o rfft24 into M (7x12 complex per expert) and copies w2 (7x6 complex).
__global__ __launch_bounds__(256)
void k_convert(const float* __restrict__ in_w, const float* __restrict__ x_w,
               const float* __restrict__ dt_w, const float* __restrict__ out_w,
               const float* __restrict__ graph,
               const float* __restrict__ fw_r, const float* __restrict__ fw_i,
               __bf16* __restrict__ in_w_sw, __bf16* __restrict__ x_w_sw,
               __bf16* __restrict__ dtw_sw, __bf16* __restrict__ out_w_sw,
               __bf16* __restrict__ graph_sw, float* __restrict__ mw) {
    int idx = blockIdx.x * 256 + threadIdx.x;
    if (idx < 131072) {            // in_w: 4e x 16nt x 4kc (K=128)
        int o = idx;
        int e = o >> 15, r = o & 32767;
        int frag = r >> 9, lane = (r >> 3) & 63, j = r & 7;
        int nt = frag >> 2, kc = frag & 3, lm = lane & 15, lq = lane >> 4;
        in_w_sw[o] = (__bf16)in_w[e * 32768 + (nt * 16 + lm) * 128 + kc * 32 + lq * 8 + j];
        return;
    }
    idx -= 131072;
    if (idx < 98304) {             // x_w: 4e x 12nt x 4kc (K=128)
        int o = idx;
        int e = o / 24576, r = o - e * 24576;
        int frag = r >> 9, lane = (r >> 3) & 63, j = r & 7;
        int nt = frag >> 2, kc = frag & 3, lm = lane & 15, lq = lane >> 4;
        x_w_sw[o] = (__bf16)x_w[e * 24576 + (nt * 16 + lm) * 128 + kc * 32 + lq * 8 + j];
        return;
    }
    idx -= 98304;
    if (idx < 16384) {             // dt_w: 4e x 8nt (K=32)
        int o = idx;
        int e = o >> 12, r = o & 4095;
        int nt = r >> 9, lane = (r >> 3) & 63, j = r & 7;
        int lm = lane & 15, lq = lane >> 4;
        dtw_sw[o] = (__bf16)dt_w[e * 4096 + (nt * 16 + lm) * 32 + lq * 8 + j];
        return;
    }
    idx -= 16384;
    if (idx < 65536) {             // out_w: 4e x 8nt x 4kc (K=128)
        int o = idx;
        int e = o >> 14, r = o & 16383;
        int frag = r >> 9, lane = (r >> 3) & 63, j = r & 7;
        int f = frag >> 2, kc = frag & 3, lm = lane & 15, lq = lane >> 4;
        out_w_sw[o] = (__bf16)out_w[e * 16384 + (f * 16 + lm) * 128 + kc * 32 + lq * 8 + j];
        return;
    }
    idx -= 65536;
    if (idx < 1572864) {           // graph: coalesced read, fragment-order write
        int bl = idx >> 14, r = idx & 16383;
        int dd = r >> 7, a = r & 127;           // src: graph[bl][dd][a], B rows=K=dd, cols=a
        int nt = a >> 4, lm = a & 15, kc = dd >> 5, lq = (dd >> 3) & 3, j = dd & 7;
        graph_sw[(size_t)bl * 16384 + ((size_t)((nt * 4 + kc) * 64 + lq * 16 + lm)) * 8 + j] =
            (__bf16)graph[(size_t)bl * 16384 + dd * 128 + a];
        return;
    }
    idx -= 1572864;
    if (idx < 336) {               // M = fw[:, :13] . D24  (7x12 complex per expert)
        int o = idx;
        int e = o / 84, r = o - e * 84;
        int o2 = r / 12, l = r - o2 * 12;
        float mr = 0.f, mi = 0.f;
        for (int k = 0; k < 13; ++k) {
            float sv, cv;
            __sincosf(6.283185307179586f * (float)(k * l) / 24.0f, &sv, &cv);
            const float wr = fw_r[e * 133 + o2 * 19 + k], wi = fw_i[e * 133 + o2 * 19 + k];
            mr += wr * cv + wi * sv;
            mi += wi * cv - wr * sv;
        }
        mw[e * 256 + (o2 * 12 + l) * 2]     = mr;
        mw[e * 256 + (o2 * 12 + l) * 2 + 1] = mi;
        return;
    }
    idx -= 336;
    if (idx < 168) {               // w2 copy (7x6 complex per expert)
        int o = idx;
        int e = o / 42, r = o - e * 42;
        int o2 = r / 6, k = r - o2 * 6;
        mw[e * 256 + 168 + (o2 * 6 + k) * 2]     = fw_r[e * 133 + o2 * 19 + 13 + k];
        mw[e * 256 + 168 + (o2 * 6 + k) * 2 + 1] = fw_i[e * 133 + o2 * 19 + 13 + k];
    }
}

// ---------------- block reductions over 128 threads (2 waves) ----------------
template <int N>
__device__ __forceinline__ void red_sum128(float* v, float* sred, int tid) {
#pragma unroll
    for (int off = 32; off; off >>= 1)
#pragma unroll
        for (int i = 0; i < N; ++i) v[i] += __shfl_xor(v[i], off, 64);
    if ((tid & 63) == 0) {
#pragma unroll
        for (int i = 0; i < N; ++i) sred[(tid >> 6) * N + i] = v[i];
    }
    __syncthreads();
#pragma unroll
    for (int i = 0; i < N; ++i) v[i] = sred[i] + sred[N + i];
    __syncthreads();
}

template <int N>
__device__ __forceinline__ void red_max128(float* v, float* sred, int tid) {
#pragma unroll
    for (int off = 32; off; off >>= 1)
#pragma unroll
        for (int i = 0; i < N; ++i) v[i] = fmaxf(v[i], __shfl_xor(v[i], off, 64));
    if ((tid & 63) == 0) {
#pragma unroll
        for (int i = 0; i < N; ++i) sred[(tid >> 6) * N + i] = v[i];
    }
    __syncthreads();
#pragma unroll
    for (int i = 0; i < N; ++i) v[i] = fmaxf(sred[i], sred[N + i]);
    __syncthreads();
}

// ---------------- K1: rmsnorm + in_proj + silu + x_proj + dt_proj + graph-mix ----------------
// grid (96, 20) x 256 (4 waves). block = (b,l) x 16-node tile.
// scanp packs (dl_mix, xs, dp, sz) as 4 x bf16 per (row,node,d).
__global__ __launch_bounds__(256)
void k_fused(const float* __restrict__ xcur, const float* __restrict__ norm_w,
             const __bf16* __restrict__ WiSw, const float* __restrict__ in_b,
             const __bf16* __restrict__ WxSw, const __bf16* __restrict__ DWSw,
             const float* __restrict__ dt_b, const __bf16* __restrict__ GSw,
             __bf16* __restrict__ scanp, float* __restrict__ bcf32, int e) {
    __shared__ __bf16 sxs[16 * 136];
    __shared__ __bf16 sdelta[16 * 136];
    __shared__ __bf16 sdel32[16 * 40];
    __shared__ float sxf[16][132];
    const int bl = blockIdx.x;
    const int n0 = blockIdx.y * 16;
    const int tid = threadIdx.x;
    const int wave = tid >> 6, lane = tid & 63;
    const int lm = lane & 15, lq = lane >> 4;
    const int b = bl / 12, l = bl - b * 12;
    const size_t rowbase = (size_t)bl * NODES + n0;

    // ---- phase 0a: stage the 16x128 x-tile through LDS (contiguous 512B wave reads) ----
    for (int i = tid; i < 1024; i += 256) {
        const int node = i >> 6, dp2 = i & 63;
        const int gn = min(n0 + node, NODES - 1);
        *(float2*)(&sxf[node][dp2 * 2]) =
            *(const float2*)(xcur + ((size_t)(b * NODES + gn) * 12 + l) * 128 + dp2 * 2);
    }
    __syncthreads();

    // ---- phase 0b: rmsnorm -> A fragments in registers ----
    float xv[4][8];
#pragma unroll
    for (int kc = 0; kc < 4; ++kc)
#pragma unroll
        for (int j = 0; j < 8; ++j) xv[kc][j] = sxf[lm][kc * 32 + lq * 8 + j];

    float ss = 0.f;
#pragma unroll
    for (int kc = 0; kc < 4; ++kc)
#pragma unroll
        for (int j = 0; j < 8; ++j) ss += xv[kc][j] * xv[kc][j];
    ss += __shfl_xor(ss, 16, 64);
    ss += __shfl_xor(ss, 32, 64);
    const float rms = rsqrtf(ss * (1.0f / 128.0f) + 1e-5f);

    bfx8 af[4];
    const float* nwp = norm_w + e * DM + lq * 8;
#pragma unroll
    for (int kc = 0; kc < 4; ++kc) {
        float4 w0 = *(const float4*)(nwp + kc * 32);
        float4 w1 = *(const float4*)(nwp + kc * 32 + 4);
        af[kc][0] = (__bf16)(xv[kc][0] * rms * w0.x);
        af[kc][1] = (__bf16)(xv[kc][1] * rms * w0.y);
        af[kc][2] = (__bf16)(xv[kc][2] * rms * w0.z);
        af[kc][3] = (__bf16)(xv[kc][3] * rms * w0.w);
        af[kc][4] = (__bf16)(xv[kc][4] * rms * w1.x);
        af[kc][5] = (__bf16)(xv[kc][5] * rms * w1.y);
        af[kc][6] = (__bf16)(xv[kc][6] * rms * w1.z);
        af[kc][7] = (__bf16)(xv[kc][7] * rms * w1.w);
    }

    // ---- prefetch phase-2 B fragments (independent of phase 1) ----
    const __bf16* WxP = WxSw + (size_t)e * 24576;
    bfx8 b2[3][4];
#pragma unroll
    for (int ntl = 0; ntl < 3; ++ntl)
#pragma unroll
        for (int kc = 0; kc < 4; ++kc)
            b2[ntl][kc] = *(const bfx8*)(WxP + (((wave * 3 + ntl) * 4 + kc) * 64 + lane) * 8);

    // ---- phase 1: in_proj ----
    const __bf16* WiP = WiSw + (size_t)e * 32768;
    f32x4 acc[4];
#pragma unroll
    for (int nt = 0; nt < 4; ++nt) acc[nt] = (f32x4){0.f, 0.f, 0.f, 0.f};
#pragma unroll
    for (int ntl = 0; ntl < 4; ++ntl) {
        const int nt = wave * 4 + ntl;
#pragma unroll
        for (int kc = 0; kc < 4; ++kc) {
            bfx8 bb = *(const bfx8*)(WiP + ((nt * 4 + kc) * 64 + lane) * 8);
            acc[ntl] = MFMA16(af[kc], bb, acc[ntl]);
        }
    }

    // ---- prefetch phase-3 + phase-4 B fragments ----
    const __bf16* DWp = DWSw + (size_t)e * 4096;
    bfx8 b3[2];
#pragma unroll
    for (int ntl = 0; ntl < 2; ++ntl)
        b3[ntl] = *(const bfx8*)(DWp + ((wave * 2 + ntl) * 64 + lane) * 8);
    const __bf16* Gp = GSw + (size_t)bl * 16384;
    bfx8 b4[2][4];
#pragma unroll
    for (int ntl = 0; ntl < 2; ++ntl)
#pragma unroll
        for (int kc = 0; kc < 4; ++kc)
            b4[ntl][kc] = *(const bfx8*)(Gp + (((wave * 2 + ntl) * 4 + kc) * 64 + lane) * 8);

    // ---- phase 1 epilogue ----
#pragma unroll
    for (int ntl = 0; ntl < 4; ++ntl) {
        const int col = wave * 64 + ntl * 16 + lm;
        const float bias = in_b[e * 256 + col];
#pragma unroll
        for (int r = 0; r < 4; ++r) {
            const int node = lq * 4 + r;
            const float v = fsilu(acc[ntl][r] + bias);
            const int ok = (n0 + node) < NODES;
            if (col < 128) {
                sxs[node * 136 + col] = (__bf16)v;
                if (ok) scanp[(rowbase + node) * 512 + col * 4 + 1] = (__bf16)v;
            } else if (ok) {
                scanp[(rowbase + node) * 512 + (col - 128) * 4 + 3] = (__bf16)v;
            }
        }
    }
    __syncthreads();

    // ---- phase 2: x_proj, A from LDS, B prefetched ----
    bfx8 ax[4];
#pragma unroll
    for (int kc = 0; kc < 4; ++kc)
        ax[kc] = *(const bfx8*)(sxs + lm * 136 + kc * 32 + lq * 8);

    f32x4 xacc[3];
#pragma unroll
    for (int nt = 0; nt < 3; ++nt) xacc[nt] = (f32x4){0.f, 0.f, 0.f, 0.f};
#pragma unroll
    for (int ntl = 0; ntl < 3; ++ntl)
#pragma unroll
        for (int kc = 0; kc < 4; ++kc)
            xacc[ntl] = MFMA16(ax[kc], b2[ntl][kc], xacc[ntl]);

#pragma unroll
    for (int ntl = 0; ntl < 3; ++ntl) {
        const int col = (wave * 3 + ntl) * 16 + lm;
#pragma unroll
        for (int r = 0; r < 4; ++r) {
            const int node = lq * 4 + r;
            const float v = xacc[ntl][r];
            const int ok = (n0 + node) < NODES;
            if (col < 32) sdel32[node * 40 + col] = (__bf16)v;
            else if (col < 64) { if (ok) bcf32[(rowbase + node) * 32 + (col - 32)] = v; }
            else if (ok) scanp[(rowbase + node) * 512 + (col - 64) * 4 + 2] = (__bf16)v;
        }
    }
    __syncthreads();

    // ---- phase 3: dt projection (K=32) ----
    bfx8 ad = *(const bfx8*)(sdel32 + lm * 40 + lq * 8);
    const f32x4 z4 = {0.f, 0.f, 0.f, 0.f};
#pragma unroll
    for (int ntl = 0; ntl < 2; ++ntl) {
        f32x4 dacc = MFMA16(ad, b3[ntl], z4);
        const int col = (wave * 2 + ntl) * 16 + lm;
        const float bias = dt_b[e * 128 + col];
#pragma unroll
        for (int r = 0; r < 4; ++r) {
            const int node = lq * 4 + r;
            sdelta[node * 136 + col] = (__bf16)fsoftplus(dacc[r] + bias);
        }
    }
    __syncthreads();

    // ---- phase 4: graph mix ----
    bfx8 ag[4];
#pragma unroll
    for (int kc = 0; kc < 4; ++kc)
        ag[kc] = *(const bfx8*)(sdelta + lm * 136 + kc * 32 + lq * 8);

#pragma unroll
    for (int ntl = 0; ntl < 2; ++ntl) {
        f32x4 gacc = z4;
#pragma unroll
        for (int kc = 0; kc < 4; ++kc)
            gacc = MFMA16(ag[kc], b4[ntl][kc], gacc);
        const int col = (wave * 2 + ntl) * 16 + lm;
#pragma unroll
        for (int r = 0; r < 4; ++r) {
            const int node = lq * 4 + r;
            if ((n0 + node) < NODES)
                scanp[(rowbase + node) * 512 + col * 4 + 0] = (__bf16)gacc[r];
        }
    }
}

// ---------------- K2: freq gating + SSM scan + gate + out_proj + residual ----------------
// grid (2456) x 128 (2 waves). One (b,n) row, one d per thread.
// All freq transforms are pre-folded matrices: compile-time C12/S12 literals +
// per-expert M/w2 in SGPRs (scalar loads). B/C via scalar loads. No twiddle recurrences.
__global__ __launch_bounds__(128)
void k_scanout(const float* __restrict__ xcur, const float* __restrict__ norm_w,
               const float* __restrict__ mw, const __bf16* __restrict__ scanp,
               const float* __restrict__ bcf32, const float* __restrict__ A_log,
               const __bf16* __restrict__ WoSw, const float* __restrict__ out_b,
               const float* __restrict__ blk_w, const float* __restrict__ blk_b,
               float* __restrict__ xout, int e, int last) {
    __shared__ float sred[24];
    __shared__ __bf16 s_out[16 * 136];
    const int row = blockIdx.x, tid = threadIdx.x;
    const int b = row / NODES, n = row - b * NODES;

    constexpr float SQ32 = 0.8660254037844386f;
    constexpr float C12[12] = {1.f, SQ32, 0.5f, 0.f, -0.5f, -SQ32, -1.f, -SQ32, -0.5f, 0.f, 0.5f, SQ32};
    constexpr float S12[12] = {0.f, 0.5f, SQ32, 1.f, SQ32, 0.5f, 0.f, -0.5f, -SQ32, -1.f, -SQ32, -0.5f};
    constexpr float LOGT[16] = {0.f, 0.6931472f, 1.0986123f, 1.3862944f, 1.6094379f, 1.7917595f,
                                1.9459101f, 2.0794415f, 2.1972246f, 2.3025851f, 2.3978953f,
                                2.4849066f, 2.5649494f, 2.6390573f, 2.7080502f, 2.7725887f};

    // ---- hoisted packed scan-input loads (latency hidden under freq section) ----
    bfx4 sc12[12];
    const size_t sb = ((size_t)(b * 12) * NODES + n) * 512 + (size_t)tid * 4;
#pragma unroll
    for (int l = 0; l < 12; ++l)
        sc12[l] = *(const bfx4*)(scanp + sb + (size_t)l * (NODES * 512));

    // ---- A-structure check via log literals (uniform, no exp) ----
    int chainOK = 1;
#pragma unroll
    for (int s = 0; s < 16; ++s)
        chainOK &= (fabsf(A_log[e * 16 + s] - LOGT[s]) < 1e-4f) ? 1 : 0;

    // ---- rmsnorm (coalesced x loads) ----
    const float* xp = xcur + (size_t)row * 1536 + tid;
    float xv[12], v[12];
#pragma unroll
    for (int l = 0; l < 12; ++l) { xv[l] = xp[l * 128]; v[l] = xv[l] * xv[l]; }
    red_sum128<12>(v, sred, tid);

    const float nrmw = norm_w[e * DM + tid];
    float xnr[12];
#pragma unroll
    for (int l = 0; l < 12; ++l)
        xnr[l] = xv[l] * rsqrtf(v[l] * (1.0f / 128.0f) + 1e-5f) * nrmw;

    // ---- f: 7 even bins of the padded rfft == rfft12, literal-coefficient FMAs ----
    float fr[7], fi[7];
#pragma unroll
    for (int o2 = 0; o2 < 7; ++o2) {
        float r = 0.f, im = 0.f;
#pragma unroll
        for (int l = 0; l < 12; ++l) {
            const int t = (o2 * l) % 12;
            r += xnr[l] * C12[t];
            im -= xnr[l] * S12[t];
        }
        fr[o2] = r; fi[o2] = im;
    }

    // ---- a7 = |f + U|^2, sorted descending ----
    float a7[7];
#pragma unroll
    for (int o2 = 0; o2 < 7; ++o2) {
        const float ar = fr[o2] + 1e-6f, ai = fi[o2] + 1e-6f;
        a7[o2] = ar * ar + ai * ai;
    }
#pragma unroll
    for (int pss = 0; pss < 6; ++pss)
#pragma unroll
        for (int j = 0; j < 6; ++j) {
            const float hi = fmaxf(a7[j], a7[j + 1]);
            const float lo = fminf(a7[j], a7[j + 1]);
            a7[j] = hi; a7[j + 1] = lo;
        }

    // ---- p = |M.xn + w2.a7|^2, M/w2 via scalar loads (uniform) ----
    const float* Me = mw + e * 256;
    float p7[7];
#pragma unroll
    for (int o2 = 0; o2 < 7; ++o2) {
        float pr = 0.f, pi = 0.f;
#pragma unroll
        for (int l = 0; l < 12; ++l) {
            pr += xnr[l] * Me[(o2 * 12 + l) * 2];
            pi += xnr[l] * Me[(o2 * 12 + l) * 2 + 1];
        }
#pragma unroll
        for (int k = 0; k < 6; ++k) {
            pr += a7[k] * Me[168 + (o2 * 6 + k) * 2];
            pi += a7[k] * Me[168 + (o2 * 6 + k) * 2 + 1];
        }
        p7[o2] = pr * pr + pi * pi;
    }

    // ---- softmax over d ----
    float m7[7], ex[7], sm[7];
#pragma unroll
    for (int o2 = 0; o2 < 7; ++o2) m7[o2] = p7[o2];
    red_max128<7>(m7, sred, tid);
#pragma unroll
    for (int o2 = 0; o2 < 7; ++o2) { ex[o2] = __expf(p7[o2] - m7[o2]); sm[o2] = ex[o2]; }
    red_sum128<7>(sm, sred, tid);

    float gr[7], gi[7];
#pragma unroll
    for (int o2 = 0; o2 < 7; ++o2) {
        const float wf = ex[o2] / sm[o2];
        gr[o2] = wf * fr[o2];
        gi[o2] = wf * fi[o2];
    }

    // ---- irfft12 with literal coefficients ----
    float xfqv[12];
#pragma unroll
    for (int l = 0; l < 12; ++l) {
        float val = gr[0] + ((l & 1) ? -gr[6] : gr[6]);
#pragma unroll
        for (int o2 = 1; o2 < 6; ++o2) {
            const int t = (o2 * l) % 12;
            val += 2.0f * (gr[o2] * C12[t] - gi[o2] * S12[t]);
        }
        xfqv[l] = val * (1.0f / 12.0f);
    }

    // ---- zero pad rows for out_proj A-tile ----
#pragma unroll
    for (int r = 12; r < 16; ++r) s_out[r * 136 + tid] = (__bf16)0.f;

    // ---- SSM scan: 16 states/thread, B/C via scalar loads, pow-tree + split y-dot ----
    float h[16];
#pragma unroll
    for (int j = 0; j < 16; ++j) h[j] = 0.f;

    if (chainOK) {
#pragma unroll
        for (int l = 0; l < 12; ++l) {
            const float dl = (float)sc12[l][0], xsv = (float)sc12[l][1];
            const float dlx = dl * xsv;
            const float* bc = bcf32 + ((size_t)(b * 12 + l) * NODES + n) * 32;
            const float q1 = __expf(-dl);
            const float q2 = q1 * q1, q4 = q2 * q2, q8 = q4 * q4;
            float pw[16];
            pw[0] = q1;        pw[1] = q2;        pw[2] = q1 * q2;   pw[3] = q4;
            pw[4] = q1 * q4;   pw[5] = q2 * q4;   pw[6] = pw[2] * q4; pw[7] = q8;
            pw[8] = q1 * q8;   pw[9] = q2 * q8;   pw[10] = pw[2] * q8; pw[11] = q4 * q8;
            pw[12] = pw[4] * q8; pw[13] = pw[5] * q8; pw[14] = pw[6] * q8; pw[15] = q8 * q8;
            float y0 = 0.f, y1 = 0.f, y2 = 0.f, y3 = 0.f;
#pragma unroll
            for (int j = 0; j < 4; ++j) {
                h[j]      = pw[j]      * h[j]      + bc[j]      * dlx;  y0 += h[j]      * bc[16 + j];
                h[j + 4]  = pw[j + 4]  * h[j + 4]  + bc[j + 4]  * dlx;  y1 += h[j + 4]  * bc[20 + j];
                h[j + 8]  = pw[j + 8]  * h[j + 8]  + bc[j + 8]  * dlx;  y2 += h[j + 8]  * bc[24 + j];
                h[j + 12] = pw[j + 12] * h[j + 12] + bc[j + 12] * dlx;  y3 += h[j + 12] * bc[28 + j];
            }
            float y = (y0 + y1) + (y2 + y3);
            y += (float)sc12[l][2] * xsv;
            const float g = y * (float)sc12[l][3] * xfqv[l];
            s_out[l * 136 + tid] = (__bf16)g;
        }
    } else {
        float As[16];
#pragma unroll
        for (int s = 0; s < 16; ++s) As[s] = -__expf(A_log[e * 16 + s]);
#pragma unroll
        for (int l = 0; l < 12; ++l) {
            const float dl = (float)sc12[l][0], xsv = (float)sc12[l][1];
            const float dlx = dl * xsv;
            const float* bc = bcf32 + ((size_t)(b * 12 + l) * NODES + n) * 32;
            float y = 0.f;
#pragma unroll
            for (int j = 0; j < 16; ++j) {
                const float a = __expf(dl * As[j]);
                h[j] = a * h[j] + bc[j] * dlx;
                y += h[j] * bc[16 + j];
            }
            y += (float)sc12[l][2] * xsv;
            const float g = y * (float)sc12[l][3] * xfqv[l];
            s_out[l * 136 + tid] = (__bf16)g;
        }
    }
    __syncthreads();

    // ---- out_proj: N=128 split 64/64 by wave, pre-swizzled weights ----
    const int wave = tid >> 6, lane = tid & 63;
    const int lm = lane & 15, lq = lane >> 4;
    const __bf16* Wop = WoSw + (size_t)e * 16384;
    bfx8 a[4];
#pragma unroll
    for (int kc = 0; kc < 4; ++kc)
        a[kc] = *(const bfx8*)(s_out + lm * 136 + kc * 32 + lq * 8);

    f32x4 acc[4];
#pragma unroll
    for (int nt = 0; nt < 4; ++nt) acc[nt] = (f32x4){0.f, 0.f, 0.f, 0.f};
#pragma unroll
    for (int nt = 0; nt < 4; ++nt) {
        const int f = wave * 4 + nt;
#pragma unroll
        for (int kc = 0; kc < 4; ++kc) {
            bfx8 bb = *(const bfx8*)(Wop + ((f * 4 + kc) * 64 + lane) * 8);
            acc[nt] = MFMA16(a[kc], bb, acc[nt]);
        }
    }

    const float bw = blk_w[e], bb2 = blk_b[e];
#pragma unroll
    for (int nt = 0; nt < 4; ++nt) {
        const int col = wave * 64 + nt * 16 + lm;
        const float ob = out_b[e * 128 + col];
#pragma unroll
        for (int r = 0; r < 4; ++r) {
            const int m = lq * 4 + r;
            if (m < 12) {
                const size_t gi = (size_t)row * 1536 + m * 128 + col;
                float vv = bw * (acc[nt][r] + ob) + bb2 + xcur[gi];
                if (last) vv = fsilu(vv);
                xout[gi] = vv;
            }
        }
    }
}

extern "C" void kernel_launch(void* const* d_in, const int* in_sizes, int n_in,
                              void* d_out, int out_size, void* d_ws, size_t ws_size,
                              hipStream_t stream) {
    (void)in_sizes; (void)n_in; (void)out_size; (void)ws_size;
    const float* x_in   = (const float*)d_in[0];
    const float* graph  = (const float*)d_in[1];
    const float* in_w   = (const float*)d_in[2];
    const float* in_b   = (const float*)d_in[3];
    const float* x_w    = (const float*)d_in[4];
    const float* dt_w   = (const float*)d_in[5];
    const float* dt_b   = (const float*)d_in[6];
    const float* A_log  = (const float*)d_in[7];
    const float* out_w  = (const float*)d_in[8];
    const float* out_b  = (const float*)d_in[9];
    const float* fw_r   = (const float*)d_in[10];
    const float* fw_i   = (const float*)d_in[11];
    const float* norm_w = (const float*)d_in[12];
    const float* blk_w  = (const float*)d_in[13];
    const float* blk_b  = (const float*)d_in[14];
    float* out = (float*)d_out;

    float* ws = (float*)d_ws;
    size_t o = 0;
    __bf16* in_w_sw  = (__bf16*)(ws + o); o += 131072 / 2;
    __bf16* x_w_sw   = (__bf16*)(ws + o); o += 98304 / 2;
    __bf16* dtw_sw   = (__bf16*)(ws + o); o += 16384 / 2;
    __bf16* out_w_sw = (__bf16*)(ws + o); o += 65536 / 2;
    __bf16* graph_sw = (__bf16*)(ws + o); o += 1572864 / 2;
    __bf16* scanp    = (__bf16*)(ws + o); o += (size_t)MROWS * 512 / 2;  // (dl,xs,dp,sz) x bf16
    float*  bcf32    = ws + o;            o += (size_t)MROWS * 32;
    float*  mw       = ws + o;            o += 1024;                      // M(7x12 cplx)+w2(7x6 cplx) per e

    // 1,884,160 weight elems + 336 M + 168 w2 = 1,884,664 -> 7362 blocks
    hipLaunchKernelGGL(k_convert, dim3(7362), dim3(256), 0, stream,
                       in_w, x_w, dt_w, out_w, graph, fw_r, fw_i,
                       in_w_sw, x_w_sw, dtw_sw, out_w_sw, graph_sw, mw);

    for (int e = 0; e < 4; ++e) {
        const float* xcur = (e == 0) ? x_in : (const float*)out;
        const int last = (e == 3) ? 1 : 0;
        hipLaunchKernelGGL(k_fused, dim3(96, 20), dim3(256), 0, stream,
                           xcur, norm_w, in_w_sw, in_b, x_w_sw, dtw_sw, dt_b, graph_sw,
                           scanp, bcf32, e);
        hipLaunchKernelGGL(k_scanout, dim3(BN), dim3(128), 0, stream,
                           xcur, norm_w, mw, scanp, bcf32, A_log,
                           out_w_sw, out_b, blk_w, blk_b, out, e, last);
    }
}

// Round 4
// 377.534 us; speedup vs baseline: 1.2327x; 1.0126x over previous
//
#include <hip/hip_runtime.h>
#include <math.h>

#define BN    2456
#define LSEQ  12
#define DM    128
#define NODES 307
#define MROWS 29472   // BN * LSEQ
#define FREQ_BLKS  1228
#define FUSED_BLKS 1920

typedef __bf16 bfx8 __attribute__((ext_vector_type(8)));
typedef __bf16 bfx4 __attribute__((ext_vector_type(4)));
typedef float  f32x4 __attribute__((ext_vector_type(4)));

#define MFMA16(a, b, c) __builtin_amdgcn_mfma_f32_16x16x32_bf16(a, b, c, 0, 0, 0)

__device__ __forceinline__ float fsilu(float v)     { return v / (1.0f + __expf(-v)); }
__device__ __forceinline__ float fsoftplus(float x) { return fmaxf(x, 0.f) + __logf(1.0f + __expf(-fabsf(x))); }

// ---------------- K0: convert + pre-swizzle weights into MFMA fragment order ----------------
// Also folds freq_proj o rfft24 into M (7x12 complex per expert) and copies w2 (7x6 complex).
__global__ __launch_bounds__(256)
void k_convert(const float* __restrict__ in_w, const float* __restrict__ x_w,
               const float* __restrict__ dt_w, const float* __restrict__ out_w,
               const float* __restrict__ graph,
               const float* __restrict__ fw_r, const float* __restrict__ fw_i,
               __bf16* __restrict__ in_w_sw, __bf16* __restrict__ x_w_sw,
               __bf16* __restrict__ dtw_sw, __bf16* __restrict__ out_w_sw,
               __bf16* __restrict__ graph_sw, float* __restrict__ mw) {
    int idx = blockIdx.x * 256 + threadIdx.x;
    if (idx < 131072) {            // in_w: 4e x 16nt x 4kc (K=128)
        int o = idx;
        int e = o >> 15, r = o & 32767;
        int frag = r >> 9, lane = (r >> 3) & 63, j = r & 7;
        int nt = frag >> 2, kc = frag & 3, lm = lane & 15, lq = lane >> 4;
        in_w_sw[o] = (__bf16)in_w[e * 32768 + (nt * 16 + lm) * 128 + kc * 32 + lq * 8 + j];
        return;
    }
    idx -= 131072;
    if (idx < 98304) {             // x_w: 4e x 12nt x 4kc (K=128)
        int o = idx;
        int e = o / 24576, r = o - e * 24576;
        int frag = r >> 9, lane = (r >> 3) & 63, j = r & 7;
        int nt = frag >> 2, kc = frag & 3, lm = lane & 15, lq = lane >> 4;
        x_w_sw[o] = (__bf16)x_w[e * 24576 + (nt * 16 + lm) * 128 + kc * 32 + lq * 8 + j];
        return;
    }
    idx -= 98304;
    if (idx < 16384) {             // dt_w: 4e x 8nt (K=32)
        int o = idx;
        int e = o >> 12, r = o & 4095;
        int nt = r >> 9, lane = (r >> 3) & 63, j = r & 7;
        int lm = lane & 15, lq = lane >> 4;
        dtw_sw[o] = (__bf16)dt_w[e * 4096 + (nt * 16 + lm) * 32 + lq * 8 + j];
        return;
    }
    idx -= 16384;
    if (idx < 65536) {             // out_w: 4e x 8nt x 4kc (K=128)
        int o = idx;
        int e = o >> 14, r = o & 16383;
        int frag = r >> 9, lane = (r >> 3) & 63, j = r & 7;
        int f = frag >> 2, kc = frag & 3, lm = lane & 15, lq = lane >> 4;
        out_w_sw[o] = (__bf16)out_w[e * 16384 + (f * 16 + lm) * 128 + kc * 32 + lq * 8 + j];
        return;
    }
    idx -= 65536;
    if (idx < 1572864) {           // graph: coalesced read, fragment-order write
        int bl = idx >> 14, r = idx & 16383;
        int dd = r >> 7, a = r & 127;           // src: graph[bl][dd][a], B rows=K=dd, cols=a
        int nt = a >> 4, lm = a & 15, kc = dd >> 5, lq = (dd >> 3) & 3, j = dd & 7;
        graph_sw[(size_t)bl * 16384 + ((size_t)((nt * 4 + kc) * 64 + lq * 16 + lm)) * 8 + j] =
            (__bf16)graph[(size_t)bl * 16384 + dd * 128 + a];
        return;
    }
    idx -= 1572864;
    if (idx < 336) {               // M = fw[:, :13] . D24  (7x12 complex per expert)
        int o = idx;
        int e = o / 84, r = o - e * 84;
        int o2 = r / 12, l = r - o2 * 12;
        float mr = 0.f, mi = 0.f;
        for (int k = 0; k < 13; ++k) {
            float sv, cv;
            __sincosf(6.283185307179586f * (float)(k * l) / 24.0f, &sv, &cv);
            const float wr = fw_r[e * 133 + o2 * 19 + k], wi = fw_i[e * 133 + o2 * 19 + k];
            mr += wr * cv + wi * sv;
            mi += wi * cv - wr * sv;
        }
        mw[e * 256 + (o2 * 12 + l) * 2]     = mr;
        mw[e * 256 + (o2 * 12 + l) * 2 + 1] = mi;
        return;
    }
    idx -= 336;
    if (idx < 168) {               // w2 copy (7x6 complex per expert)
        int o = idx;
        int e = o / 42, r = o - e * 42;
        int o2 = r / 6, k = r - o2 * 6;
        mw[e * 256 + 168 + (o2 * 6 + k) * 2]     = fw_r[e * 133 + o2 * 19 + 13 + k];
        mw[e * 256 + 168 + (o2 * 6 + k) * 2 + 1] = fw_i[e * 133 + o2 * 19 + 13 + k];
    }
}

// ---------------- K1: co-dispatched {freq rows} + {fused GEMM tiles} ----------------
// grid = FREQ_BLKS + FUSED_BLKS blocks x 256 threads.
//  bid <  FREQ_BLKS : freq gating for 2 rows (128 threads each) -> xfq_bf
//  bid >= FREQ_BLKS : rmsnorm + in_proj + silu + x_proj + dt_proj + graph-mix for
//                     one (b,l) x 16-node tile; scanp written via LDS-staged coalesced dump.
__global__ __launch_bounds__(256)
void k_fused(const float* __restrict__ xcur, const float* __restrict__ norm_w,
             const __bf16* __restrict__ WiSw, const float* __restrict__ in_b,
             const __bf16* __restrict__ WxSw, const __bf16* __restrict__ DWSw,
             const float* __restrict__ dt_b, const __bf16* __restrict__ GSw,
             const float* __restrict__ mw,
             __bf16* __restrict__ scanp, float* __restrict__ bcf32,
             __bf16* __restrict__ xfq_bf, int e) {
    const int tid = threadIdx.x;

    if (blockIdx.x < FREQ_BLKS) {
        // ================== freq path: 2 rows per block ==================
        __shared__ float sred2[2][2][12];
        const int hh = tid >> 7, t7 = tid & 127;
        const int lane = tid & 63, w2 = (tid >> 6) & 1;
        const int row = blockIdx.x * 2 + hh;
        const int b = row / NODES, n = row - b * NODES;

        constexpr float SQ32 = 0.8660254037844386f;
        constexpr float C12[12] = {1.f, SQ32, 0.5f, 0.f, -0.5f, -SQ32, -1.f, -SQ32, -0.5f, 0.f, 0.5f, SQ32};
        constexpr float S12[12] = {0.f, 0.5f, SQ32, 1.f, SQ32, 0.5f, 0.f, -0.5f, -SQ32, -1.f, -SQ32, -0.5f};

        const float* xp = xcur + (size_t)row * 1536 + t7;
        float xv[12], v[12];
#pragma unroll
        for (int l = 0; l < 12; ++l) { xv[l] = xp[l * 128]; v[l] = xv[l] * xv[l]; }
        // sum-reduce over the row's 128 channels (2 waves)
#pragma unroll
        for (int off = 32; off; off >>= 1)
#pragma unroll
            for (int i = 0; i < 12; ++i) v[i] += __shfl_xor(v[i], off, 64);
        if (lane == 0) {
#pragma unroll
            for (int i = 0; i < 12; ++i) sred2[hh][w2][i] = v[i];
        }
        __syncthreads();
#pragma unroll
        for (int i = 0; i < 12; ++i) v[i] = sred2[hh][0][i] + sred2[hh][1][i];
        __syncthreads();

        const float nrmw = norm_w[e * DM + t7];
        float xnr[12];
#pragma unroll
        for (int l = 0; l < 12; ++l)
            xnr[l] = xv[l] * rsqrtf(v[l] * (1.0f / 128.0f) + 1e-5f) * nrmw;

        // f = rfft12 (even bins of padded rfft24), literal coefficients
        float fr[7], fi[7];
#pragma unroll
        for (int o2 = 0; o2 < 7; ++o2) {
            float r = 0.f, im = 0.f;
#pragma unroll
            for (int l = 0; l < 12; ++l) {
                const int t = (o2 * l) % 12;
                r += xnr[l] * C12[t];
                im -= xnr[l] * S12[t];
            }
            fr[o2] = r; fi[o2] = im;
        }

        float a7[7];
#pragma unroll
        for (int o2 = 0; o2 < 7; ++o2) {
            const float ar = fr[o2] + 1e-6f, ai = fi[o2] + 1e-6f;
            a7[o2] = ar * ar + ai * ai;
        }
#pragma unroll
        for (int pss = 0; pss < 6; ++pss)
#pragma unroll
            for (int j = 0; j < 6; ++j) {
                const float hi = fmaxf(a7[j], a7[j + 1]);
                const float lo = fminf(a7[j], a7[j + 1]);
                a7[j] = hi; a7[j + 1] = lo;
            }

        const float* Me = mw + e * 256;
        float p7[7];
#pragma unroll
        for (int o2 = 0; o2 < 7; ++o2) {
            float pr = 0.f, pi = 0.f;
#pragma unroll
            for (int l = 0; l < 12; ++l) {
                pr += xnr[l] * Me[(o2 * 12 + l) * 2];
                pi += xnr[l] * Me[(o2 * 12 + l) * 2 + 1];
            }
#pragma unroll
            for (int k = 0; k < 6; ++k) {
                pr += a7[k] * Me[168 + (o2 * 6 + k) * 2];
                pi += a7[k] * Me[168 + (o2 * 6 + k) * 2 + 1];
            }
            p7[o2] = pr * pr + pi * pi;
        }

        // softmax over channels
        float m7[7];
#pragma unroll
        for (int i = 0; i < 7; ++i) m7[i] = p7[i];
#pragma unroll
        for (int off = 32; off; off >>= 1)
#pragma unroll
            for (int i = 0; i < 7; ++i) m7[i] = fmaxf(m7[i], __shfl_xor(m7[i], off, 64));
        if (lane == 0) {
#pragma unroll
            for (int i = 0; i < 7; ++i) sred2[hh][w2][i] = m7[i];
        }
        __syncthreads();
#pragma unroll
        for (int i = 0; i < 7; ++i) m7[i] = fmaxf(sred2[hh][0][i], sred2[hh][1][i]);
        __syncthreads();

        float ex[7], sm[7];
#pragma unroll
        for (int i = 0; i < 7; ++i) { ex[i] = __expf(p7[i] - m7[i]); sm[i] = ex[i]; }
#pragma unroll
        for (int off = 32; off; off >>= 1)
#pragma unroll
            for (int i = 0; i < 7; ++i) sm[i] += __shfl_xor(sm[i], off, 64);
        if (lane == 0) {
#pragma unroll
            for (int i = 0; i < 7; ++i) sred2[hh][w2][i] = sm[i];
        }
        __syncthreads();
#pragma unroll
        for (int i = 0; i < 7; ++i) sm[i] = sred2[hh][0][i] + sred2[hh][1][i];

        float gr[7], gi[7];
#pragma unroll
        for (int o2 = 0; o2 < 7; ++o2) {
            const float wf = ex[o2] / sm[o2];
            gr[o2] = wf * fr[o2];
            gi[o2] = wf * fi[o2];
        }

        // irfft12 + store
        const size_t xb = ((size_t)(b * 12) * NODES + n) * 128 + t7;
#pragma unroll
        for (int l = 0; l < 12; ++l) {
            float val = gr[0] + ((l & 1) ? -gr[6] : gr[6]);
#pragma unroll
            for (int o2 = 1; o2 < 6; ++o2) {
                const int t = (o2 * l) % 12;
                val += 2.0f * (gr[o2] * C12[t] - gi[o2] * S12[t]);
            }
            xfq_bf[xb + (size_t)l * (NODES * 128)] = (__bf16)(val * (1.0f / 12.0f));
        }
        return;
    }

    // ================== fused GEMM path ==================
    __shared__ __bf16 sxs[16 * 136];
    __shared__ __bf16 sdelta[16 * 136];
    __shared__ __bf16 sdel32[16 * 40];
    __shared__ __align__(16) char sraw[16 * 520 * 2];   // union: sxf (f32 16x132) / sdump (bf16 16x520)
    float  (*sxf)[132]  = (float (*)[132])sraw;
    __bf16 (*sdump)[520] = (__bf16 (*)[520])sraw;

    const int bid = blockIdx.x - FREQ_BLKS;
    const int bl = bid / 20;
    const int n0 = (bid - bl * 20) * 16;
    const int wave = tid >> 6, lane = tid & 63;
    const int lm = lane & 15, lq = lane >> 4;
    const int b = bl / 12, l = bl - b * 12;
    const size_t rowbase = (size_t)bl * NODES + n0;

    // ---- phase 0a: stage the 16x128 x-tile through LDS (contiguous wave reads) ----
    for (int i = tid; i < 1024; i += 256) {
        const int node = i >> 6, dp2 = i & 63;
        const int gn = min(n0 + node, NODES - 1);
        *(float2*)(&sxf[node][dp2 * 2]) =
            *(const float2*)(xcur + ((size_t)(b * NODES + gn) * 12 + l) * 128 + dp2 * 2);
    }
    __syncthreads();

    // ---- phase 0b: rmsnorm -> A fragments in registers ----
    float xv[4][8];
#pragma unroll
    for (int kc = 0; kc < 4; ++kc)
#pragma unroll
        for (int j = 0; j < 8; ++j) xv[kc][j] = sxf[lm][kc * 32 + lq * 8 + j];

    float ss = 0.f;
#pragma unroll
    for (int kc = 0; kc < 4; ++kc)
#pragma unroll
        for (int j = 0; j < 8; ++j) ss += xv[kc][j] * xv[kc][j];
    ss += __shfl_xor(ss, 16, 64);
    ss += __shfl_xor(ss, 32, 64);
    const float rms = rsqrtf(ss * (1.0f / 128.0f) + 1e-5f);

    bfx8 af[4];
    const float* nwp = norm_w + e * DM + lq * 8;
#pragma unroll
    for (int kc = 0; kc < 4; ++kc) {
        float4 w0 = *(const float4*)(nwp + kc * 32);
        float4 w1 = *(const float4*)(nwp + kc * 32 + 4);
        af[kc][0] = (__bf16)(xv[kc][0] * rms * w0.x);
        af[kc][1] = (__bf16)(xv[kc][1] * rms * w0.y);
        af[kc][2] = (__bf16)(xv[kc][2] * rms * w0.z);
        af[kc][3] = (__bf16)(xv[kc][3] * rms * w0.w);
        af[kc][4] = (__bf16)(xv[kc][4] * rms * w1.x);
        af[kc][5] = (__bf16)(xv[kc][5] * rms * w1.y);
        af[kc][6] = (__bf16)(xv[kc][6] * rms * w1.z);
        af[kc][7] = (__bf16)(xv[kc][7] * rms * w1.w);
    }
    __syncthreads();   // sxf dead -> sraw reusable as sdump

    // ---- prefetch phase-2 B fragments ----
    const __bf16* WxP = WxSw + (size_t)e * 24576;
    bfx8 b2[3][4];
#pragma unroll
    for (int ntl = 0; ntl < 3; ++ntl)
#pragma unroll
        for (int kc = 0; kc < 4; ++kc)
            b2[ntl][kc] = *(const bfx8*)(WxP + (((wave * 3 + ntl) * 4 + kc) * 64 + lane) * 8);

    // ---- phase 1: in_proj ----
    const __bf16* WiP = WiSw + (size_t)e * 32768;
    f32x4 acc[4];
#pragma unroll
    for (int nt = 0; nt < 4; ++nt) acc[nt] = (f32x4){0.f, 0.f, 0.f, 0.f};
#pragma unroll
    for (int ntl = 0; ntl < 4; ++ntl) {
        const int nt = wave * 4 + ntl;
#pragma unroll
        for (int kc = 0; kc < 4; ++kc) {
            bfx8 bb = *(const bfx8*)(WiP + ((nt * 4 + kc) * 64 + lane) * 8);
            acc[ntl] = MFMA16(af[kc], bb, acc[ntl]);
        }
    }

    // ---- prefetch phase-3 + phase-4 B fragments ----
    const __bf16* DWp = DWSw + (size_t)e * 4096;
    bfx8 b3[2];
#pragma unroll
    for (int ntl = 0; ntl < 2; ++ntl)
        b3[ntl] = *(const bfx8*)(DWp + ((wave * 2 + ntl) * 64 + lane) * 8);
    const __bf16* Gp = GSw + (size_t)bl * 16384;
    bfx8 b4[2][4];
#pragma unroll
    for (int ntl = 0; ntl < 2; ++ntl)
#pragma unroll
        for (int kc = 0; kc < 4; ++kc)
            b4[ntl][kc] = *(const bfx8*)(Gp + (((wave * 2 + ntl) * 4 + kc) * 64 + lane) * 8);

    // ---- phase 1 epilogue: xs -> sxs + sdump ch1, sz -> sdump ch3 ----
#pragma unroll
    for (int ntl = 0; ntl < 4; ++ntl) {
        const int col = wave * 64 + ntl * 16 + lm;
        const float bias = in_b[e * 256 + col];
#pragma unroll
        for (int r = 0; r < 4; ++r) {
            const int node = lq * 4 + r;
            const float v = fsilu(acc[ntl][r] + bias);
            if (col < 128) {
                sxs[node * 136 + col] = (__bf16)v;
                sdump[node][col * 4 + 1] = (__bf16)v;
            } else {
                sdump[node][(col - 128) * 4 + 3] = (__bf16)v;
            }
        }
    }
    __syncthreads();

    // ---- phase 2: x_proj ----
    bfx8 ax[4];
#pragma unroll
    for (int kc = 0; kc < 4; ++kc)
        ax[kc] = *(const bfx8*)(sxs + lm * 136 + kc * 32 + lq * 8);

    f32x4 xacc[3];
#pragma unroll
    for (int nt = 0; nt < 3; ++nt) xacc[nt] = (f32x4){0.f, 0.f, 0.f, 0.f};
#pragma unroll
    for (int ntl = 0; ntl < 3; ++ntl)
#pragma unroll
        for (int kc = 0; kc < 4; ++kc)
            xacc[ntl] = MFMA16(ax[kc], b2[ntl][kc], xacc[ntl]);

#pragma unroll
    for (int ntl = 0; ntl < 3; ++ntl) {
        const int col = (wave * 3 + ntl) * 16 + lm;
#pragma unroll
        for (int r = 0; r < 4; ++r) {
            const int node = lq * 4 + r;
            const float v = xacc[ntl][r];
            if (col < 32) sdel32[node * 40 + col] = (__bf16)v;
            else if (col < 64) { if ((n0 + node) < NODES) bcf32[(rowbase + node) * 32 + (col - 32)] = v; }
            else sdump[node][(col - 64) * 4 + 2] = (__bf16)v;
        }
    }
    __syncthreads();

    // ---- phase 3: dt projection (K=32) ----
    bfx8 ad = *(const bfx8*)(sdel32 + lm * 40 + lq * 8);
    const f32x4 z4 = {0.f, 0.f, 0.f, 0.f};
#pragma unroll
    for (int ntl = 0; ntl < 2; ++ntl) {
        f32x4 dacc = MFMA16(ad, b3[ntl], z4);
        const int col = (wave * 2 + ntl) * 16 + lm;
        const float bias = dt_b[e * 128 + col];
#pragma unroll
        for (int r = 0; r < 4; ++r) {
            const int node = lq * 4 + r;
            sdelta[node * 136 + col] = (__bf16)fsoftplus(dacc[r] + bias);
        }
    }
    __syncthreads();

    // ---- phase 4: graph mix -> sdump ch0 ----
    bfx8 ag[4];
#pragma unroll
    for (int kc = 0; kc < 4; ++kc)
        ag[kc] = *(const bfx8*)(sdelta + lm * 136 + kc * 32 + lq * 8);

#pragma unroll
    for (int ntl = 0; ntl < 2; ++ntl) {
        f32x4 gacc = z4;
#pragma unroll
        for (int kc = 0; kc < 4; ++kc)
            gacc = MFMA16(ag[kc], b4[ntl][kc], gacc);
        const int col = (wave * 2 + ntl) * 16 + lm;
#pragma unroll
        for (int r = 0; r < 4; ++r) {
            const int node = lq * 4 + r;
            sdump[node][col * 4 + 0] = (__bf16)gacc[r];
        }
    }
    __syncthreads();

    // ---- coalesced dump: 16 KB LDS tile -> scanp (1 KB contiguous per wave-instr) ----
    __bf16* dst = scanp + rowbase * 512;
#pragma unroll
    for (int k = 0; k < 4; ++k) {
        const int c = k * 256 + tid;
        const int node = c >> 6;
        if ((n0 + node) < NODES)
            *(bfx8*)(dst + (size_t)c * 8) = *(const bfx8*)(&sdump[node][(c & 63) * 8]);
    }
}

// ---------------- K2: SSM scan + gate + out_proj + residual ----------------
// grid (2456) x 128. One (b,n) row, one d per thread. All inputs hoisted.
__global__ __launch_bounds__(128)
void k_scanout(const float* __restrict__ xcur, const __bf16* __restrict__ scanp,
               const float* __restrict__ bcf32, const __bf16* __restrict__ xfq_bf,
               const float* __restrict__ A_log, const __bf16* __restrict__ WoSw,
               const float* __restrict__ out_b, const float* __restrict__ blk_w,
               const float* __restrict__ blk_b, float* __restrict__ xout, int e, int last) {
    __shared__ __bf16 s_out[16 * 136];
    const int row = blockIdx.x, tid = threadIdx.x;
    const int b = row / NODES, n = row - b * NODES;

    constexpr float LOGT[16] = {0.f, 0.6931472f, 1.0986123f, 1.3862944f, 1.6094379f, 1.7917595f,
                                1.9459101f, 2.0794415f, 2.1972246f, 2.3025851f, 2.3978953f,
                                2.4849066f, 2.5649494f, 2.6390573f, 2.7080502f, 2.7725887f};

    // ---- hoisted loads ----
    bfx4 sc12[12];
    const size_t sb = ((size_t)(b * 12) * NODES + n) * 512 + (size_t)tid * 4;
#pragma unroll
    for (int l = 0; l < 12; ++l)
        sc12[l] = *(const bfx4*)(scanp + sb + (size_t)l * (NODES * 512));

    __bf16 xq[12];
    const size_t xb = ((size_t)(b * 12) * NODES + n) * 128 + tid;
#pragma unroll
    for (int l = 0; l < 12; ++l)
        xq[l] = xfq_bf[xb + (size_t)l * (NODES * 128)];

    // ---- A-structure check via log literals (uniform) ----
    int chainOK = 1;
#pragma unroll
    for (int s = 0; s < 16; ++s)
        chainOK &= (fabsf(A_log[e * 16 + s] - LOGT[s]) < 1e-4f) ? 1 : 0;

    // ---- zero pad rows for out_proj A-tile ----
#pragma unroll
    for (int r = 12; r < 16; ++r) s_out[r * 136 + tid] = (__bf16)0.f;

    // ---- SSM scan: 16 states/thread ----
    float h[16];
#pragma unroll
    for (int j = 0; j < 16; ++j) h[j] = 0.f;

    if (chainOK) {
        float q1a[12];
#pragma unroll
        for (int l = 0; l < 12; ++l) q1a[l] = __expf(-(float)sc12[l][0]);
#pragma unroll
        for (int l = 0; l < 12; ++l) {
            const float dl = (float)sc12[l][0], xsv = (float)sc12[l][1];
            const float dlx = dl * xsv;
            const float* bc = bcf32 + ((size_t)(b * 12 + l) * NODES + n) * 32;
            const float q1 = q1a[l];
            const float q2 = q1 * q1, q4 = q2 * q2, q8 = q4 * q4;
            float pw[16];
            pw[0] = q1;        pw[1] = q2;        pw[2] = q1 * q2;    pw[3] = q4;
            pw[4] = q1 * q4;   pw[5] = q2 * q4;   pw[6] = pw[2] * q4; pw[7] = q8;
            pw[8] = q1 * q8;   pw[9] = q2 * q8;   pw[10] = pw[2] * q8; pw[11] = q4 * q8;
            pw[12] = pw[4] * q8; pw[13] = pw[5] * q8; pw[14] = pw[6] * q8; pw[15] = q8 * q8;
            float y0 = 0.f, y1 = 0.f, y2 = 0.f, y3 = 0.f;
#pragma unroll
            for (int j = 0; j < 4; ++j) {
                h[j]      = pw[j]      * h[j]      + bc[j]      * dlx;  y0 += h[j]      * bc[16 + j];
                h[j + 4]  = pw[j + 4]  * h[j + 4]  + bc[j + 4]  * dlx;  y1 += h[j + 4]  * bc[20 + j];
                h[j + 8]  = pw[j + 8]  * h[j + 8]  + bc[j + 8]  * dlx;  y2 += h[j + 8]  * bc[24 + j];
                h[j + 12] = pw[j + 12] * h[j + 12] + bc[j + 12] * dlx;  y3 += h[j + 12] * bc[28 + j];
            }
            float y = (y0 + y1) + (y2 + y3);
            y += (float)sc12[l][2] * xsv;
            const float g = y * (float)sc12[l][3] * (float)xq[l];
            s_out[l * 136 + tid] = (__bf16)g;
        }
    } else {
        float As[16];
#pragma unroll
        for (int s = 0; s < 16; ++s) As[s] = -__expf(A_log[e * 16 + s]);
#pragma unroll
        for (int l = 0; l < 12; ++l) {
            const float dl = (float)sc12[l][0], xsv = (float)sc12[l][1];
            const float dlx = dl * xsv;
            const float* bc = bcf32 + ((size_t)(b * 12 + l) * NODES + n) * 32;
            float y = 0.f;
#pragma unroll
            for (int j = 0; j < 16; ++j) {
                const float a = __expf(dl * As[j]);
                h[j] = a * h[j] + bc[j] * dlx;
                y += h[j] * bc[16 + j];
            }
            y += (float)sc12[l][2] * xsv;
            const float g = y * (float)sc12[l][3] * (float)xq[l];
            s_out[l * 136 + tid] = (__bf16)g;
        }
    }
    __syncthreads();

    // ---- out_proj: N=128 split 64/64 by wave, pre-swizzled weights ----
    const int wave = tid >> 6, lane = tid & 63;
    const int lm = lane & 15, lq = lane >> 4;
    const __bf16* Wop = WoSw + (size_t)e * 16384;
    bfx8 a[4];
#pragma unroll
    for (int kc = 0; kc < 4; ++kc)
        a[kc] = *(const bfx8*)(s_out + lm * 136 + kc * 32 + lq * 8);

    f32x4 acc[4];
#pragma unroll
    for (int nt = 0; nt < 4; ++nt) acc[nt] = (f32x4){0.f, 0.f, 0.f, 0.f};
#pragma unroll
    for (int nt = 0; nt < 4; ++nt) {
        const int f = wave * 4 + nt;
#pragma unroll
        for (int kc = 0; kc < 4; ++kc) {
            bfx8 bb = *(const bfx8*)(Wop + ((f * 4 + kc) * 64 + lane) * 8);
            acc[nt] = MFMA16(a[kc], bb, acc[nt]);
        }
    }

    const float bw = blk_w[e], bb2 = blk_b[e];
#pragma unroll
    for (int nt = 0; nt < 4; ++nt) {
        const int col = wave * 64 + nt * 16 + lm;
        const float ob = out_b[e * 128 + col];
#pragma unroll
        for (int r = 0; r < 4; ++r) {
            const int m = lq * 4 + r;
            if (m < 12) {
                const size_t gi = (size_t)row * 1536 + m * 128 + col;
                float vv = bw * (acc[nt][r] + ob) + bb2 + xcur[gi];
                if (last) vv = fsilu(vv);
                xout[gi] = vv;
            }
        }
    }
}

extern "C" void kernel_launch(void* const* d_in, const int* in_sizes, int n_in,
                              void* d_out, int out_size, void* d_ws, size_t ws_size,
                              hipStream_t stream) {
    (void)in_sizes; (void)n_in; (void)out_size; (void)ws_size;
    const float* x_in   = (const float*)d_in[0];
    const float* graph  = (const float*)d_in[1];
    const float* in_w   = (const float*)d_in[2];
    const float* in_b   = (const float*)d_in[3];
    const float* x_w    = (const float*)d_in[4];
    const float* dt_w   = (const float*)d_in[5];
    const float* dt_b   = (const float*)d_in[6];
    const float* A_log  = (const float*)d_in[7];
    const float* out_w  = (const float*)d_in[8];
    const float* out_b  = (const float*)d_in[9];
    const float* fw_r   = (const float*)d_in[10];
    const float* fw_i   = (const float*)d_in[11];
    const float* norm_w = (const float*)d_in[12];
    const float* blk_w  = (const float*)d_in[13];
    const float* blk_b  = (const float*)d_in[14];
    float* out = (float*)d_out;

    float* ws = (float*)d_ws;
    size_t o = 0;
    __bf16* in_w_sw  = (__bf16*)(ws + o); o += 131072 / 2;
    __bf16* x_w_sw   = (__bf16*)(ws + o); o += 98304 / 2;
    __bf16* dtw_sw   = (__bf16*)(ws + o); o += 16384 / 2;
    __bf16* out_w_sw = (__bf16*)(ws + o); o += 65536 / 2;
    __bf16* graph_sw = (__bf16*)(ws + o); o += 1572864 / 2;
    const size_t NE = (size_t)MROWS * 128;
    __bf16* scanp    = (__bf16*)(ws + o); o += (size_t)MROWS * 512 / 2;  // (dl,xs,dp,sz) x bf16
    __bf16* xfq_bf   = (__bf16*)(ws + o); o += NE / 2;
    float*  bcf32    = ws + o;            o += (size_t)MROWS * 32;
    float*  mw       = ws + o;            o += 1024;                      // M + w2 per expert

    // 1,884,160 weight elems + 336 M + 168 w2 -> 7362 blocks
    hipLaunchKernelGGL(k_convert, dim3(7362), dim3(256), 0, stream,
                       in_w, x_w, dt_w, out_w, graph, fw_r, fw_i,
                       in_w_sw, x_w_sw, dtw_sw, out_w_sw, graph_sw, mw);

    for (int e = 0; e < 4; ++e) {
        const float* xcur = (e == 0) ? x_in : (const float*)out;
        const int last = (e == 3) ? 1 : 0;
        hipLaunchKernelGGL(k_fused, dim3(FREQ_BLKS + FUSED_BLKS), dim3(256), 0, stream,
                           xcur, norm_w, in_w_sw, in_b, x_w_sw, dtw_sw, dt_b, graph_sw,
                           mw, scanp, bcf32, xfq_bf, e);
        hipLaunchKernelGGL(k_scanout, dim3(BN), dim3(128), 0, stream,
                           xcur, scanp, bcf32, xfq_bf, A_log,
                           out_w_sw, out_b, blk_w, blk_b, out, e, last);
    }
}